// Round 6
// baseline (382.438 us; speedup 1.0000x reference)
//
#include <hip/hip_runtime.h>
#include <hip/hip_bf16.h>
#include <hip/hip_fp16.h>
#include <stdint.h>

// RelationMultiHeadAttention on MI355X.
// R6: k_score1 -> tiled gll GEMM; k_s2v2 -> 4 blocks/CU (2-deep rk, 2KB rv
// half-chunks); k_val1 d-split; gll staging for k_projqkv/k_out B-operand.
// Pipeline: k_prep -> k_projqkv -> k_qt -> k_score1 -> k_s2v2 -> k_val1 -> k_out

typedef __attribute__((ext_vector_type(4))) float f32x4;
typedef __attribute__((ext_vector_type(8))) short s16x8;

#define MFMA16(A, B, C) __builtin_amdgcn_mfma_f32_16x16x32_bf16(A, B, C, 0, 0, 0)

__device__ __forceinline__ uint16_t f2bf(float x) {
  uint32_t u = __float_as_uint(x);
  u += 0x7fffu + ((u >> 16) & 1u);
  return (uint16_t)(u >> 16);
}
__device__ __forceinline__ float bf2f(uint16_t u) {
  return __uint_as_float((uint32_t)u << 16);
}
__device__ __forceinline__ uint16_t f2h(float x) {
  __half h = __float2half_rn(x);
  return *reinterpret_cast<uint16_t*>(&h);
}
__device__ __forceinline__ float h2f(uint16_t u) {
  __half h = *reinterpret_cast<__half*>(&u);
  return __half2float(h);
}

__device__ __forceinline__ s16x8 pack8(float4 a, float4 b) {
  s16x8 r;
  r[0] = (short)f2bf(a.x); r[1] = (short)f2bf(a.y); r[2] = (short)f2bf(a.z); r[3] = (short)f2bf(a.w);
  r[4] = (short)f2bf(b.x); r[5] = (short)f2bf(b.y); r[6] = (short)f2bf(b.z); r[7] = (short)f2bf(b.w);
  return r;
}

__device__ __forceinline__ void gll16(const void* g, void* l) {
  __builtin_amdgcn_global_load_lds(
      (const __attribute__((address_space(1))) uint32_t*)(g),
      (__attribute__((address_space(3))) uint32_t*)(l), 16, 0, 0);
}

// ---------------------------------------------------------------------------
// K0: weight prep (unchanged).
// ---------------------------------------------------------------------------
__global__ __launch_bounds__(256) void k_prep(
    const float* __restrict__ Wq, const float* __restrict__ Wk,
    const float* __restrict__ Wv, const float* __restrict__ Wo,
    const float* __restrict__ Wrk, const float* __restrict__ Wrv,
    uint16_t* __restrict__ WqT, uint16_t* __restrict__ WkT,
    uint16_t* __restrict__ WvT, uint16_t* __restrict__ WoT,
    uint16_t* __restrict__ WrkB, uint16_t* __restrict__ WrvT) {
  int z = blockIdx.y;
  int t = threadIdx.x;
  if (z == 4) {
    if (blockIdx.x == 0) {
      for (int i = t; i < 128 * 64; i += 256) WrkB[i] = f2bf(Wrk[i]);
      for (int i = t; i < 64 * 128; i += 256) {
        int d = i >> 7, r = i & 127;
        WrvT[i] = f2bf(Wrv[r * 64 + d]);
      }
    }
    return;
  }
  const float* W = (z == 0) ? Wq : (z == 1) ? Wk : (z == 2) ? Wv : Wo;
  uint16_t* O = (z == 0) ? WqT : (z == 1) ? WkT : (z == 2) ? WvT : WoT;
  int tk = (blockIdx.x >> 4) * 64;
  int tn = (blockIdx.x & 15) * 64;
  __shared__ float tile[64][65];
  {
    int kk = t >> 2, c0 = (t & 3) * 16;
    const float* src = W + (size_t)(tk + kk) * 1024 + tn + c0;
#pragma unroll
    for (int i = 0; i < 16; i += 4) {
      float4 v = *(const float4*)(src + i);
      tile[kk][c0 + i + 0] = v.x; tile[kk][c0 + i + 1] = v.y;
      tile[kk][c0 + i + 2] = v.z; tile[kk][c0 + i + 3] = v.w;
    }
  }
  __syncthreads();
  {
    int n_loc = t >> 2;
    int n = tn + n_loc;
#pragma unroll
    for (int cc = 0; cc < 2; ++cc) {
      int c = (t & 3) * 2 + cc;
      int csrc = c ^ (n & 7);
      s16x8 pk;
#pragma unroll
      for (int j = 0; j < 8; ++j) pk[j] = (short)f2bf(tile[csrc * 8 + j][n_loc]);
      *reinterpret_cast<s16x8*>(O + (size_t)n * 1024 + tk + c * 8) = pk;
    }
  }
}

// ---------------------------------------------------------------------------
// K1: projections; Bs staged via gll (WT pre-swizzled -> linear copy).
// ---------------------------------------------------------------------------
__global__ __launch_bounds__(256) void k_projqkv(
    const float* __restrict__ Xq, const float* __restrict__ Xk,
    const float* __restrict__ Xv, const uint16_t* __restrict__ WTbase,
    const float* __restrict__ bq, const float* __restrict__ bk,
    const float* __restrict__ bv, uint16_t* __restrict__ outbase) {
  int mode = blockIdx.z;
  const float* X = (mode == 0) ? Xq : (mode == 1) ? Xk : Xv;
  const float* bias = (mode == 0) ? bq : (mode == 1) ? bk : bv;
  const uint16_t* WT = WTbase + (size_t)mode * (1u << 20);
  uint16_t* out = outbase + (size_t)mode * (2u << 20);

  __shared__ alignas(16) uint16_t As[128 * 64];
  __shared__ alignas(16) uint16_t Bs[128 * 64];
  int t = threadIdx.x, lane = t & 63, w = t >> 6, lr = lane & 15, lg = lane >> 4;
  int m0 = blockIdx.x * 128, n0 = blockIdx.y * 128;
  int wm = (w >> 1) * 64, wn = (w & 1) * 64;
  f32x4 acc[4][4];
#pragma unroll
  for (int i = 0; i < 4; ++i)
#pragma unroll
    for (int j = 0; j < 4; ++j) acc[i][j] = (f32x4){0.f, 0.f, 0.f, 0.f};
  int srow = t >> 1, sh = t & 1;
  for (int ko = 0; ko < 16; ++ko) {
    __syncthreads();
    {
      // Bs via gll: u = i*256+t -> row u>>3, chunk u&7 (linear, pre-swizzled)
#pragma unroll
      for (int i = 0; i < 4; ++i) {
        int u = i * 256 + t;
        int row = u >> 3, c2 = u & 7;
        gll16(WT + (size_t)(n0 + row) * 1024 + ko * 64 + c2 * 8, (char*)Bs + u * 16);
      }
      const float* src = X + (size_t)(m0 + srow) * 1024 + ko * 64 + sh * 32;
#pragma unroll
      for (int c = 0; c < 4; ++c) {
        float4 v0 = *(const float4*)(src + c * 8);
        float4 v1 = *(const float4*)(src + c * 8 + 4);
        s16x8 pk = pack8(v0, v1);
        *reinterpret_cast<s16x8*>((char*)As + srow * 128 +
                                  ((((sh * 4 + c) * 16)) ^ ((srow & 7) << 4))) = pk;
      }
    }
    __syncthreads();
#pragma unroll
    for (int kk = 0; kk < 2; ++kk) {
      s16x8 af[4], bf[4];
#pragma unroll
      for (int mt = 0; mt < 4; ++mt) {
        int row = wm + mt * 16 + lr;
        af[mt] = *(const s16x8*)((const char*)As + row * 128 +
                                 (((kk * 32 + lg * 8) * 2) ^ ((row & 7) << 4)));
      }
#pragma unroll
      for (int nt = 0; nt < 4; ++nt) {
        int row = wn + nt * 16 + lr;
        bf[nt] = *(const s16x8*)((const char*)Bs + row * 128 +
                                 (((kk * 32 + lg * 8) * 2) ^ ((row & 7) << 4)));
      }
#pragma unroll
      for (int mt = 0; mt < 4; ++mt)
#pragma unroll
        for (int nt = 0; nt < 4; ++nt)
          acc[mt][nt] = MFMA16(af[mt], bf[nt], acc[mt][nt]);
    }
  }
  float sc = (mode == 1) ? 0.125f : 1.0f;
#pragma unroll
  for (int mt = 0; mt < 4; ++mt) {
#pragma unroll
    for (int nt = 0; nt < 4; ++nt) {
      int col = n0 + wn + nt * 16 + lr;
      float bcol = bias[col];
      if (mode != 2) {
#pragma unroll
        for (int r = 0; r < 4; ++r) {
          int row = m0 + wm + mt * 16 + lg * 4 + r;
          out[(size_t)row * 1024 + col] = f2bf((acc[mt][nt][r] + bcol) * sc);
        }
      } else {
        int row0 = m0 + wm + mt * 16 + lg * 4;
        int b = row0 >> 9, n = row0 & 511;
        int h = col >> 6, d = col & 63;
        ushort4 pk;
        pk.x = f2bf(acc[mt][nt][0] + bcol);
        pk.y = f2bf(acc[mt][nt][1] + bcol);
        pk.z = f2bf(acc[mt][nt][2] + bcol);
        pk.w = f2bf(acc[mt][nt][3] + bcol);
        *reinterpret_cast<ushort4*>(out + ((size_t)(b * 16 + h) * 64 + d) * 512 + n) = pk;
      }
    }
  }
}

// ---------------------------------------------------------------------------
// K1b: qt = qh @ Wrk^T (unchanged).
// ---------------------------------------------------------------------------
__global__ __launch_bounds__(256) void k_qt(
    const uint16_t* __restrict__ qh, const uint16_t* __restrict__ WrkB,
    uint16_t* __restrict__ qt) {
  int t = threadIdx.x, lane = t & 63, w = t >> 6, lr = lane & 15, lg = lane >> 4;
  int row0 = blockIdx.x * 64 + w * 16;
  f32x4 acc[8];
#pragma unroll
  for (int i = 0; i < 8; ++i) acc[i] = (f32x4){0.f, 0.f, 0.f, 0.f};
  s16x8 af[2];
#pragma unroll
  for (int kk = 0; kk < 2; ++kk)
    af[kk] = *(const s16x8*)(qh + (size_t)(row0 + lr) * 64 + kk * 32 + lg * 8);
#pragma unroll
  for (int rt = 0; rt < 8; ++rt) {
#pragma unroll
    for (int kk = 0; kk < 2; ++kk) {
      s16x8 bf = *(const s16x8*)(WrkB + (size_t)(rt * 16 + lr) * 64 + kk * 32 + lg * 8);
      acc[rt] = MFMA16(af[kk], bf, acc[rt]);
    }
  }
#pragma unroll
  for (int rt = 0; rt < 8; ++rt)
#pragma unroll
    for (int r = 0; r < 4; ++r)
      qt[(size_t)(row0 + lg * 4 + r) * 128 + rt * 16 + lr] = f2bf(acc[rt][r]);
}

// ---------------------------------------------------------------------------
// K2: S1[mrow][h][nsw] fp16 = qh.kh^T. Tiled 128x128, gll-staged, swizzled.
// grid (mt*4+nt = 16, h = 16, b = 4). nsw = n ^ ((h&7)<<3).
// ---------------------------------------------------------------------------
__global__ __launch_bounds__(256) void k_score1(
    const uint16_t* __restrict__ qh, const uint16_t* __restrict__ kh,
    uint16_t* __restrict__ S1) {
  __shared__ alignas(16) uint16_t As[128 * 64];  // qh rows (m)
  __shared__ alignas(16) uint16_t Bs[128 * 64];  // kh rows (n)
  int t = threadIdx.x, lane = t & 63, w = t >> 6, lr = lane & 15, lg = lane >> 4;
  int mt = blockIdx.x >> 2, nt = blockIdx.x & 3, h = blockIdx.y, b = blockIdx.z;
  int m0 = mt * 128, n0 = nt * 128;
  const char* qg = (const char*)(qh + (size_t)(b * 512 + m0) * 1024 + h * 64);
  const char* kg = (const char*)(kh + (size_t)(b * 512 + n0) * 1024 + h * 64);
#pragma unroll
  for (int i = 0; i < 4; ++i) {
    int u = i * 256 + t;            // 0..1023: row u>>3, dst chunk u&7
    int row = u >> 3;
    int cs = (u & 7) ^ (row & 7);   // pre-swizzled source chunk
    gll16(qg + (size_t)row * 2048 + cs * 16, (char*)As + u * 16);
    gll16(kg + (size_t)row * 2048 + cs * 16, (char*)Bs + u * 16);
  }
  __syncthreads();
  int wm = (w >> 1) * 64, wn = (w & 1) * 64;
  f32x4 acc[4][4];
#pragma unroll
  for (int i = 0; i < 4; ++i)
#pragma unroll
    for (int j = 0; j < 4; ++j) acc[i][j] = (f32x4){0.f, 0.f, 0.f, 0.f};
#pragma unroll
  for (int kk = 0; kk < 2; ++kk) {
    s16x8 af[4], bf[4];
#pragma unroll
    for (int mtt = 0; mtt < 4; ++mtt) {
      int row = wm + mtt * 16 + lr;
      af[mtt] = *(const s16x8*)((const char*)As + row * 128 +
                                (((kk * 4 + lg) ^ (row & 7)) * 16));
    }
#pragma unroll
    for (int ntt = 0; ntt < 4; ++ntt) {
      int row = wn + ntt * 16 + lr;
      bf[ntt] = *(const s16x8*)((const char*)Bs + row * 128 +
                                (((kk * 4 + lg) ^ (row & 7)) * 16));
    }
    // MFMA16(B,A): D row-dim (lg*4+r) <-> kh rows (n), col (lr) <-> qh rows (m)
#pragma unroll
    for (int mtt = 0; mtt < 4; ++mtt)
#pragma unroll
      for (int ntt = 0; ntt < 4; ++ntt)
        acc[mtt][ntt] = MFMA16(bf[ntt], af[mtt], acc[mtt][ntt]);
  }
  int hsw = (h & 7) << 3;
#pragma unroll
  for (int mtt = 0; mtt < 4; ++mtt) {
#pragma unroll
    for (int ntt = 0; ntt < 4; ++ntt) {
      int m = b * 512 + m0 + wm + mtt * 16 + lr;
      int nsw = (n0 + wn + ntt * 16 + lg * 4) ^ hsw;
      ushort4 u4;
      u4.x = f2h(acc[mtt][ntt][0]); u4.y = f2h(acc[mtt][ntt][1]);
      u4.z = f2h(acc[mtt][ntt][2]); u4.w = f2h(acc[mtt][ntt][3]);
      *(ushort4*)(S1 + (size_t)m * 8192 + h * 512 + nsw) = u4;
    }
  }
}

// ---------------------------------------------------------------------------
// K3: per-(b,m) relation streams. Wave-private gll pipelines, 4 blocks/CU.
// rk: 32 steps x 2KB (16 n-rows x one 128B k-slice), 2-deep, vmcnt(2).
// rv: 32 half-chunks x 2KB (32 n-rows x 16 rc-cols), 2-deep, vmcnt(2);
//     each half-chunk feeds one K=32 MFMA of one accumulator.
// ---------------------------------------------------------------------------
#define RKSTEP(s)                                                              \
  {                                                                            \
    asm volatile("s_waitcnt vmcnt(%0)" :: "i"(((s) < 31) ? 2 : 0) : "memory"); \
    const char* bp_ = wpriv + ((s) & 1) * 2048 + lr * 128;                     \
    float4 v0_ = *(const float4*)(bp_ + (((lg * 2 + 0) ^ (lr & 7)) * 16));     \
    float4 v1_ = *(const float4*)(bp_ + (((lg * 2 + 1) ^ (lr & 7)) * 16));     \
    acc[(s) >> 2] = MFMA16(aqt[(s) & 3], pack8(v0_, v1_), acc[(s) >> 2]);      \
    if ((s) + 2 < 32) {                                                        \
      const int s2_ = (s) + 2;                                                 \
      const char* src_ = rkb + (size_t)((s2_ >> 2) * 64 + w * 16 + r_lo) * 512 \
                         + (s2_ & 3) * 128 + c16s * 16;                        \
      char* dst_ = wpriv + (s2_ & 1) * 2048 + lane * 16;                       \
      gll16(src_, dst_);                                                       \
      gll16(src_ + 8 * 512, dst_ + 1024);                                      \
    }                                                                          \
  }

#define RVI(c)                                                                 \
  { _Pragma("unroll")                                                          \
    for (int i_ = 0; i_ < 2; ++i_) {                                           \
      int u_ = i_ * 64 + lane;                                                 \
      gll16(rvb + (size_t)(((c) >> 1) * 32 + (u_ >> 2)) * 512 + w * 128 +      \
                ((c) & 1) * 64 + (u_ & 3) * 16,                                \
            wpriv + ((c) & 1) * 2048 + u_ * 16);                               \
    } }

#define RVC(c, accv)                                                           \
  {                                                                            \
    s16x8 a_ = *(const s16x8*)((const char*)att_lds + lr * 1024 +              \
        (((uint32_t)(((c) >> 1) * 64 + lg * 16)) ^ ((uint32_t)(lr & 7) << 4)));\
    const float* vb_ = (const float*)(wpriv + ((c) & 1) * 2048);               \
    s16x8 bf_;                                                                 \
    _Pragma("unroll")                                                          \
    for (int i = 0; i < 8; ++i) bf_[i] = (short)f2bf(vb_[(lg * 8 + i) * 16 + lr]); \
    accv = MFMA16(a_, bf_, accv);                                              \
  }

__global__ __launch_bounds__(256, 4) void k_s2v2(
    const uint16_t* __restrict__ qt, const float* __restrict__ rk,
    const float* __restrict__ rv, uint16_t* SATT,
    const uint16_t* __restrict__ WrvT, const float* __restrict__ brv,
    uint16_t* __restrict__ V2) {
  int bm = blockIdx.x;
  int t = threadIdx.x, lane = t & 63, w = t >> 6, lr = lane & 15, lg = lane >> 4;
  __shared__ alignas(16) char stream_lds[16384];      // 4KB per wave, private
  __shared__ alignas(16) uint16_t att_lds[16 * 512];  // S1 fp16 -> att bf16
  __shared__ alignas(16) uint16_t arv_lds[16 * 128];
  __shared__ float red[2][16][4];
  char* wpriv = stream_lds + w * 4096;
  const int r_lo = lane >> 3;               // 0..7
  const int c16s = (lane & 7) ^ r_lo;       // swizzled rk source chunk

  s16x8 aqt[4];
#pragma unroll
  for (int kk = 0; kk < 4; ++kk)
    aqt[kk] = *(const s16x8*)(qt + ((size_t)bm * 16 + lr) * 128 + kk * 32 + lg * 8);
  const char* s1g = (const char*)(SATT + (size_t)bm * 8192);
#pragma unroll
  for (int i = 0; i < 4; ++i)
    gll16(s1g + i * 4096 + t * 16, (char*)att_lds + i * 4096 + t * 16);
  asm volatile("s_waitcnt vmcnt(0)" ::: "memory");

  // rk prologue: steps 0,1
  const char* rkb = (const char*)(rk + (size_t)bm * 65536);
#pragma unroll
  for (int s2 = 0; s2 < 2; ++s2) {
    const char* src_ = rkb + (size_t)(w * 16 + r_lo) * 512 + s2 * 128 + c16s * 16;
    char* dst_ = wpriv + s2 * 2048 + lane * 16;
    gll16(src_, dst_);
    gll16(src_ + 8 * 512, dst_ + 1024);
  }

  f32x4 acc[8];
#pragma unroll
  for (int j = 0; j < 8; ++j) acc[j] = (f32x4){0.f, 0.f, 0.f, 0.f};

  RKSTEP(0)  RKSTEP(1)  RKSTEP(2)  RKSTEP(3)  RKSTEP(4)  RKSTEP(5)  RKSTEP(6)  RKSTEP(7)
  RKSTEP(8)  RKSTEP(9)  RKSTEP(10) RKSTEP(11) RKSTEP(12) RKSTEP(13) RKSTEP(14) RKSTEP(15)
  RKSTEP(16) RKSTEP(17) RKSTEP(18) RKSTEP(19) RKSTEP(20) RKSTEP(21) RKSTEP(22) RKSTEP(23)
  RKSTEP(24) RKSTEP(25) RKSTEP(26) RKSTEP(27) RKSTEP(28) RKSTEP(29) RKSTEP(30) RKSTEP(31)

  // rv prologue: half-chunks 0,1 arrive during softmax
  const char* rvb = (const char*)(rv + (size_t)bm * 65536);
  RVI(0) RVI(1)
  __syncthreads();  // S1 (all waves' quarters) visible

  // ---- S1 add (fp16 from att_lds)
#pragma unroll
  for (int idx = 0; idx < 8; ++idx) {
#pragma unroll
    for (int r = 0; r < 4; ++r) {
      int h = lg * 4 + r;
      int n = idx * 64 + w * 16 + lr;
      uint16_t s1v = *(const uint16_t*)((const char*)att_lds + h * 1024 +
                     (((uint32_t)n * 2) ^ ((uint32_t)(h & 7) << 4)));
      acc[idx][r] += h2f(s1v);
    }
  }

  // ---- softmax
  float mrow[4], inv[4];
#pragma unroll
  for (int r = 0; r < 4; ++r) {
    float mx = acc[0][r];
#pragma unroll
    for (int j = 1; j < 8; ++j) mx = fmaxf(mx, acc[j][r]);
#pragma unroll
    for (int off = 1; off < 16; off <<= 1) mx = fmaxf(mx, __shfl_xor(mx, off, 64));
    mrow[r] = mx;
  }
  if (lr == 0) {
#pragma unroll
    for (int r = 0; r < 4; ++r) red[0][lg * 4 + r][w] = mrow[r];
  }
  __syncthreads();
#pragma unroll
  for (int r = 0; r < 4; ++r) {
    const float* p = red[0][lg * 4 + r];
    mrow[r] = fmaxf(fmaxf(p[0], p[1]), fmaxf(p[2], p[3]));
  }
#pragma unroll
  for (int r = 0; r < 4; ++r) {
    float s = 0.f;
#pragma unroll
    for (int j = 0; j < 8; ++j) {
      float pj = __expf(acc[j][r] - mrow[r]);
      acc[j][r] = pj;
      s += pj;
    }
#pragma unroll
    for (int off = 1; off < 16; off <<= 1) s += __shfl_xor(s, off, 64);
    inv[r] = s;
  }
  if (lr == 0) {
#pragma unroll
    for (int r = 0; r < 4; ++r) red[1][lg * 4 + r][w] = inv[r];
  }
  __syncthreads();
#pragma unroll
  for (int r = 0; r < 4; ++r) {
    const float* p = red[1][lg * 4 + r];
    inv[r] = 1.f / (p[0] + p[1] + p[2] + p[3]);
  }
#pragma unroll
  for (int r = 0; r < 4; ++r) {
    int h = lg * 4 + r;
#pragma unroll
    for (int idx = 0; idx < 8; ++idx) {
      int n = idx * 64 + w * 16 + lr;
      uint32_t off = (uint32_t)h * 1024 + (((uint32_t)n * 2) ^ ((uint32_t)(h & 7) << 4));
      *(uint16_t*)((char*)att_lds + off) = f2bf(acc[idx][r] * inv[r]);
    }
  }
  __syncthreads();  // att published

  // ---- rv stream: 32 half-chunks, pairs keep acc indices static
  f32x4 arv0 = (f32x4){0.f, 0.f, 0.f, 0.f}, arv1 = arv0;
#pragma unroll 1
  for (int cp = 0; cp < 14; ++cp) {
    asm volatile("s_waitcnt vmcnt(2)" ::: "memory");
    RVC(2 * cp, arv0)
    RVI(2 * cp + 2)
    asm volatile("s_waitcnt vmcnt(2)" ::: "memory");
    RVC(2 * cp + 1, arv1)
    RVI(2 * cp + 3)
  }
  asm volatile("s_waitcnt vmcnt(2)" ::: "memory");
  RVC(28, arv0)
  RVI(30)
  asm volatile("s_waitcnt vmcnt(2)" ::: "memory");
  RVC(29, arv1)
  RVI(31)
  asm volatile("s_waitcnt vmcnt(2)" ::: "memory");
  RVC(30, arv0)
  asm volatile("s_waitcnt vmcnt(0)" ::: "memory");
  RVC(31, arv1)

  // ---- arv -> LDS, val2 = arv @ Wrv + brv -> V2
#pragma unroll
  for (int r = 0; r < 4; ++r) {
    int h = lg * 4 + r;
    uint32_t rc0 = (uint32_t)(w * 32 + lr) * 2;
    uint32_t rc1 = (uint32_t)(w * 32 + 16 + lr) * 2;
    *(uint16_t*)((char*)arv_lds + h * 256 + (rc0 ^ ((uint32_t)(h & 7) << 4))) = f2bf(arv0[r]);
    *(uint16_t*)((char*)arv_lds + h * 256 + (rc1 ^ ((uint32_t)(h & 7) << 4))) = f2bf(arv1[r]);
  }
  __syncthreads();
  f32x4 vacc = (f32x4){0.f, 0.f, 0.f, 0.f};
#pragma unroll
  for (int kk = 0; kk < 4; ++kk) {
    uint32_t rb = (uint32_t)(kk * 32 + lg * 8) * 2;
    s16x8 a = *(const s16x8*)((const char*)arv_lds + lr * 256 +
                              (rb ^ ((uint32_t)(lr & 7) << 4)));
    s16x8 bfw = *(const s16x8*)(WrvT + (size_t)(w * 16 + lr) * 128 + kk * 32 + lg * 8);
    vacc = MFMA16(a, bfw, vacc);
  }
  float bias = brv[w * 16 + lr];
#pragma unroll
  for (int r = 0; r < 4; ++r)
    V2[(size_t)bm * 1024 + (lg * 4 + r) * 64 + w * 16 + lr] = f2bf(vacc[r] + bias);

  // ---- att (bf16) -> global, in place over S1 (fire-and-forget)
#pragma unroll
  for (int i = 0; i < 4; ++i) {
    s16x8 vv = *(const s16x8*)((const char*)att_lds + i * 4096 + t * 16);
    *(s16x8*)((char*)SATT + (size_t)bm * 16384 + i * 4096 + t * 16) = vv;
  }
}

// ---------------------------------------------------------------------------
// K4: val = att @ vh + V2 -> VALB. Grid (16: mt x dh, 16 h, 4 b).
// ---------------------------------------------------------------------------
__global__ __launch_bounds__(256) void k_val1(
    const uint16_t* __restrict__ vhT, const uint16_t* __restrict__ ATT,
    const uint16_t* __restrict__ V2, uint16_t* __restrict__ VALB) {
  int t = threadIdx.x, lane = t & 63, w = t >> 6, lr = lane & 15, lg = lane >> 4;
  int mt = blockIdx.x >> 1, dh = blockIdx.x & 1, h = blockIdx.y, b = blockIdx.z;
  int mb = mt * 64 + w * 16;
  const uint16_t* vrow = vhT + ((size_t)((b * 16 + h) * 64) + dh * 32 + lr) * 512 + lg * 8;
  const uint16_t* arow = ATT + (size_t)(b * 512 + mb + lr) * 8192 + h * 512;
  f32x4 acc[2];
#pragma unroll
  for (int j = 0; j < 2; ++j) acc[j] = (f32x4){0.f, 0.f, 0.f, 0.f};
#pragma unroll 4
  for (int kk = 0; kk < 16; ++kk) {
    int nsw = (kk * 32 + lg * 8) ^ ((h & 7) << 3);
    s16x8 a0 = *(const s16x8*)(arow + nsw);
#pragma unroll
    for (int dt = 0; dt < 2; ++dt) {
      s16x8 vf = *(const s16x8*)(vrow + (size_t)dt * 16 * 512 + kk * 32);
      acc[dt] = MFMA16(vf, a0, acc[dt]);
    }
  }
#pragma unroll
  for (int dt = 0; dt < 2; ++dt) {
    size_t adr = (size_t)(b * 512 + mb + lr) * 1024 + h * 64 + dh * 32 + dt * 16 + lg * 4;
    ushort4 v2v = *(const ushort4*)(V2 + adr);
    ushort4 o;
    o.x = f2bf(acc[dt][0] + bf2f(v2v.x));
    o.y = f2bf(acc[dt][1] + bf2f(v2v.y));
    o.z = f2bf(acc[dt][2] + bf2f(v2v.z));
    o.w = f2bf(acc[dt][3] + bf2f(v2v.w));
    *(ushort4*)(VALB + adr) = o;
  }
}

// ---------------------------------------------------------------------------
// K5: out = VAL @ Wo + bo; Bs staged via gll.
// ---------------------------------------------------------------------------
__global__ __launch_bounds__(256) void k_out(
    const uint16_t* __restrict__ A, const uint16_t* __restrict__ WT,
    const float* __restrict__ bias, float* __restrict__ out) {
  __shared__ alignas(16) uint16_t As[128 * 64];
  __shared__ alignas(16) uint16_t Bs[128 * 64];
  int t = threadIdx.x, lane = t & 63, w = t >> 6, lr = lane & 15, lg = lane >> 4;
  int m0 = blockIdx.x * 128, n0 = blockIdx.y * 128;
  int wm = (w >> 1) * 64, wn = (w & 1) * 64;
  f32x4 acc[4][4];
#pragma unroll
  for (int i = 0; i < 4; ++i)
#pragma unroll
    for (int j = 0; j < 4; ++j) acc[i][j] = (f32x4){0.f, 0.f, 0.f, 0.f};
  int srow = t >> 1, sh = t & 1;
  for (int ko = 0; ko < 16; ++ko) {
    __syncthreads();
    {
#pragma unroll
      for (int i = 0; i < 4; ++i) {
        int u = i * 256 + t;
        int row = u >> 3, c2 = u & 7;
        gll16(WT + (size_t)(n0 + row) * 1024 + ko * 64 + c2 * 8, (char*)Bs + u * 16);
      }
      const uint16_t* asrc = A + (size_t)(m0 + srow) * 1024 + ko * 64 + sh * 32;
#pragma unroll
      for (int c = 0; c < 4; ++c) {
        s16x8 va = *(const s16x8*)(asrc + c * 8);
        *reinterpret_cast<s16x8*>((char*)As + srow * 128 +
                                  ((((sh * 4 + c) * 16)) ^ ((srow & 7) << 4))) = va;
      }
    }
    __syncthreads();
#pragma unroll
    for (int kk = 0; kk < 2; ++kk) {
      s16x8 af[4], bf[4];
#pragma unroll
      for (int mt = 0; mt < 4; ++mt) {
        int row = wm + mt * 16 + lr;
        af[mt] = *(const s16x8*)((const char*)As + row * 128 +
                                 (((kk * 32 + lg * 8) * 2) ^ ((row & 7) << 4)));
      }
#pragma unroll
      for (int nt = 0; nt < 4; ++nt) {
        int row = wn + nt * 16 + lr;
        bf[nt] = *(const s16x8*)((const char*)Bs + row * 128 +
                                 (((kk * 32 + lg * 8) * 2) ^ ((row & 7) << 4)));
      }
#pragma unroll
      for (int mt = 0; mt < 4; ++mt)
#pragma unroll
        for (int nt = 0; nt < 4; ++nt)
          acc[mt][nt] = MFMA16(af[mt], bf[nt], acc[mt][nt]);
    }
  }
#pragma unroll
  for (int mt = 0; mt < 4; ++mt) {
#pragma unroll
    for (int nt = 0; nt < 4; ++nt) {
      int col = n0 + wn + nt * 16 + lr;
      float bcol = bias[col];
#pragma unroll
      for (int r = 0; r < 4; ++r) {
        int row = m0 + wm + mt * 16 + lg * 4 + r;
        out[(size_t)row * 1024 + col] = acc[mt][nt][r] + bcol;
      }
    }
  }
}

// ---------------------------------------------------------------------------
extern "C" void kernel_launch(void* const* d_in, const int* in_sizes, int n_in,
                              void* d_out, int out_size, void* d_ws, size_t ws_size,
                              hipStream_t stream) {
  const float* q   = (const float*)d_in[0];
  const float* k_  = (const float*)d_in[1];
  const float* v   = (const float*)d_in[2];
  const float* r_k = (const float*)d_in[3];
  const float* r_v = (const float*)d_in[4];
  const float* Wq  = (const float*)d_in[5];
  const float* bq  = (const float*)d_in[6];
  const float* Wk  = (const float*)d_in[7];
  const float* bk  = (const float*)d_in[8];
  const float* Wv  = (const float*)d_in[9];
  const float* bv  = (const float*)d_in[10];
  const float* Wrk = (const float*)d_in[11];
  // d_in[12] = brk: softmax-invariant, unused
  const float* Wrv = (const float*)d_in[13];
  const float* brv = (const float*)d_in[14];
  const float* Wo  = (const float*)d_in[15];
  const float* bo  = (const float*)d_in[16];
  (void)in_sizes; (void)n_in; (void)out_size;

  char* ws = (char*)d_ws;
  uint16_t* WqT  = (uint16_t*)(ws + (size_t)(0));
  uint16_t* WkT  = (uint16_t*)(ws + (size_t)(2u << 20));
  uint16_t* WvT  = (uint16_t*)(ws + (size_t)(4u << 20));
  uint16_t* WoT  = (uint16_t*)(ws + (size_t)(6u << 20));
  uint16_t* WrkB = (uint16_t*)(ws + (size_t)(8u << 20));
  uint16_t* WrvT = (uint16_t*)(ws + (size_t)(8u << 20) + (64u << 10));
  uint16_t* QH   = (uint16_t*)(ws + (size_t)(16u << 20));
  uint16_t* KH   = (uint16_t*)(ws + (size_t)(20u << 20));
  uint16_t* VHT  = (uint16_t*)(ws + (size_t)(24u << 20));
  uint16_t* QT   = (uint16_t*)(ws + (size_t)(28u << 20));
  uint16_t* VALB = (uint16_t*)(ws + (size_t)(36u << 20));
  uint16_t* V2   = (uint16_t*)(ws + (size_t)(16u << 20));  // QH slot, dead after score1
  uint16_t* SATT = (uint16_t*)(ws + (size_t)(40u << 20));  // 33.6 MB
  if (ws_size < (size_t)(74u << 20)) return;  // need 74 MB of scratch

  dim3 blk(256, 1, 1);
  k_prep<<<dim3(256, 5, 1), blk, 0, stream>>>(Wq, Wk, Wv, Wo, Wrk, Wrv,
                                              WqT, WkT, WvT, WoT, WrkB, WrvT);
  k_projqkv<<<dim3(16, 8, 3), blk, 0, stream>>>(q, k_, v, WqT, bq, bk, bv, QH);
  k_qt<<<dim3(512, 1, 1), blk, 0, stream>>>(QH, WrkB, QT);
  k_score1<<<dim3(16, 16, 4), blk, 0, stream>>>(QH, KH, SATT);
  k_s2v2<<<dim3(2048, 1, 1), blk, 0, stream>>>(QT, r_k, r_v, SATT, WrvT, brv, V2);
  k_val1<<<dim3(16, 16, 4), blk, 0, stream>>>(VHT, SATT, V2, VALB);
  k_out<<<dim3(16, 8, 1), blk, 0, stream>>>(VALB, WoT, bo, (float*)d_out);
}

// Round 7
// 372.294 us; speedup vs baseline: 1.0272x; 1.0272x over previous
//
#include <hip/hip_runtime.h>
#include <hip/hip_bf16.h>
#include <hip/hip_fp16.h>
#include <stdint.h>

// RelationMultiHeadAttention on MI355X.
// R7: cvt_pk_bf16 packing (4x fewer VALU ops on stream consume), k_s2v2 S1
// stage overlapped under rk stream (recounted vmcnt), rv prefetch after
// barrier (real overlap), k_qt fused into k_score1.
// Pipeline: k_prep -> k_projqkv -> k_score1qt -> k_s2v2 -> k_val1 -> k_out

typedef __attribute__((ext_vector_type(4))) float f32x4;
typedef __attribute__((ext_vector_type(8))) short s16x8;

#define MFMA16(A, B, C) __builtin_amdgcn_mfma_f32_16x16x32_bf16(A, B, C, 0, 0, 0)

__device__ __forceinline__ uint16_t f2bf(float x) {
  uint32_t u = __float_as_uint(x);
  u += 0x7fffu + ((u >> 16) & 1u);
  return (uint16_t)(u >> 16);
}
__device__ __forceinline__ float bf2f(uint16_t u) {
  return __uint_as_float((uint32_t)u << 16);
}
__device__ __forceinline__ uint16_t f2h(float x) {
  __half h = __float2half_rn(x);
  return *reinterpret_cast<uint16_t*>(&h);
}
__device__ __forceinline__ float h2f(uint16_t u) {
  __half h = *reinterpret_cast<__half*>(&u);
  return __half2float(h);
}

// v_cvt_pk_bf16_f32: two f32 -> packed 2x bf16 (RNE), 1 VALU op per pair.
__device__ __forceinline__ uint32_t cvtpk(float lo, float hi) {
  uint32_t r;
  asm("v_cvt_pk_bf16_f32 %0, %1, %2" : "=v"(r) : "v"(lo), "v"(hi));
  return r;
}

__device__ __forceinline__ s16x8 pack8(float4 a, float4 b) {
  union { uint32_t u[4]; s16x8 v; } r;
  r.u[0] = cvtpk(a.x, a.y);
  r.u[1] = cvtpk(a.z, a.w);
  r.u[2] = cvtpk(b.x, b.y);
  r.u[3] = cvtpk(b.z, b.w);
  return r.v;
}

__device__ __forceinline__ void gll16(const void* g, void* l) {
  __builtin_amdgcn_global_load_lds(
      (const __attribute__((address_space(1))) uint32_t*)(g),
      (__attribute__((address_space(3))) uint32_t*)(l), 16, 0, 0);
}

// ---------------------------------------------------------------------------
// K0: weight prep (unchanged).
// ---------------------------------------------------------------------------
__global__ __launch_bounds__(256) void k_prep(
    const float* __restrict__ Wq, const float* __restrict__ Wk,
    const float* __restrict__ Wv, const float* __restrict__ Wo,
    const float* __restrict__ Wrk, const float* __restrict__ Wrv,
    uint16_t* __restrict__ WqT, uint16_t* __restrict__ WkT,
    uint16_t* __restrict__ WvT, uint16_t* __restrict__ WoT,
    uint16_t* __restrict__ WrkB, uint16_t* __restrict__ WrvT) {
  int z = blockIdx.y;
  int t = threadIdx.x;
  if (z == 4) {
    if (blockIdx.x == 0) {
      for (int i = t; i < 128 * 64; i += 256) WrkB[i] = f2bf(Wrk[i]);
      for (int i = t; i < 64 * 128; i += 256) {
        int d = i >> 7, r = i & 127;
        WrvT[i] = f2bf(Wrv[r * 64 + d]);
      }
    }
    return;
  }
  const float* W = (z == 0) ? Wq : (z == 1) ? Wk : (z == 2) ? Wv : Wo;
  uint16_t* O = (z == 0) ? WqT : (z == 1) ? WkT : (z == 2) ? WvT : WoT;
  int tk = (blockIdx.x >> 4) * 64;
  int tn = (blockIdx.x & 15) * 64;
  __shared__ float tile[64][65];
  {
    int kk = t >> 2, c0 = (t & 3) * 16;
    const float* src = W + (size_t)(tk + kk) * 1024 + tn + c0;
#pragma unroll
    for (int i = 0; i < 16; i += 4) {
      float4 v = *(const float4*)(src + i);
      tile[kk][c0 + i + 0] = v.x; tile[kk][c0 + i + 1] = v.y;
      tile[kk][c0 + i + 2] = v.z; tile[kk][c0 + i + 3] = v.w;
    }
  }
  __syncthreads();
  {
    int n_loc = t >> 2;
    int n = tn + n_loc;
#pragma unroll
    for (int cc = 0; cc < 2; ++cc) {
      int c = (t & 3) * 2 + cc;
      int csrc = c ^ (n & 7);
      s16x8 pk;
#pragma unroll
      for (int j = 0; j < 8; ++j) pk[j] = (short)f2bf(tile[csrc * 8 + j][n_loc]);
      *reinterpret_cast<s16x8*>(O + (size_t)n * 1024 + tk + c * 8) = pk;
    }
  }
}

// ---------------------------------------------------------------------------
// K1: projections; Bs staged via gll, As packed via cvt_pk.
// ---------------------------------------------------------------------------
__global__ __launch_bounds__(256) void k_projqkv(
    const float* __restrict__ Xq, const float* __restrict__ Xk,
    const float* __restrict__ Xv, const uint16_t* __restrict__ WTbase,
    const float* __restrict__ bq, const float* __restrict__ bk,
    const float* __restrict__ bv, uint16_t* __restrict__ outbase) {
  int mode = blockIdx.z;
  const float* X = (mode == 0) ? Xq : (mode == 1) ? Xk : Xv;
  const float* bias = (mode == 0) ? bq : (mode == 1) ? bk : bv;
  const uint16_t* WT = WTbase + (size_t)mode * (1u << 20);
  uint16_t* out = outbase + (size_t)mode * (2u << 20);

  __shared__ alignas(16) uint16_t As[128 * 64];
  __shared__ alignas(16) uint16_t Bs[128 * 64];
  int t = threadIdx.x, lane = t & 63, w = t >> 6, lr = lane & 15, lg = lane >> 4;
  int m0 = blockIdx.x * 128, n0 = blockIdx.y * 128;
  int wm = (w >> 1) * 64, wn = (w & 1) * 64;
  f32x4 acc[4][4];
#pragma unroll
  for (int i = 0; i < 4; ++i)
#pragma unroll
    for (int j = 0; j < 4; ++j) acc[i][j] = (f32x4){0.f, 0.f, 0.f, 0.f};
  int srow = t >> 1, sh = t & 1;
  for (int ko = 0; ko < 16; ++ko) {
    __syncthreads();
    {
#pragma unroll
      for (int i = 0; i < 4; ++i) {
        int u = i * 256 + t;
        int row = u >> 3, c2 = u & 7;
        gll16(WT + (size_t)(n0 + row) * 1024 + ko * 64 + c2 * 8, (char*)Bs + u * 16);
      }
      const float* src = X + (size_t)(m0 + srow) * 1024 + ko * 64 + sh * 32;
#pragma unroll
      for (int c = 0; c < 4; ++c) {
        float4 v0 = *(const float4*)(src + c * 8);
        float4 v1 = *(const float4*)(src + c * 8 + 4);
        s16x8 pk = pack8(v0, v1);
        *reinterpret_cast<s16x8*>((char*)As + srow * 128 +
                                  ((((sh * 4 + c) * 16)) ^ ((srow & 7) << 4))) = pk;
      }
    }
    __syncthreads();
#pragma unroll
    for (int kk = 0; kk < 2; ++kk) {
      s16x8 af[4], bf[4];
#pragma unroll
      for (int mt = 0; mt < 4; ++mt) {
        int row = wm + mt * 16 + lr;
        af[mt] = *(const s16x8*)((const char*)As + row * 128 +
                                 (((kk * 32 + lg * 8) * 2) ^ ((row & 7) << 4)));
      }
#pragma unroll
      for (int nt = 0; nt < 4; ++nt) {
        int row = wn + nt * 16 + lr;
        bf[nt] = *(const s16x8*)((const char*)Bs + row * 128 +
                                 (((kk * 32 + lg * 8) * 2) ^ ((row & 7) << 4)));
      }
#pragma unroll
      for (int mt = 0; mt < 4; ++mt)
#pragma unroll
        for (int nt = 0; nt < 4; ++nt)
          acc[mt][nt] = MFMA16(af[mt], bf[nt], acc[mt][nt]);
    }
  }
  float sc = (mode == 1) ? 0.125f : 1.0f;
#pragma unroll
  for (int mt = 0; mt < 4; ++mt) {
#pragma unroll
    for (int nt = 0; nt < 4; ++nt) {
      int col = n0 + wn + nt * 16 + lr;
      float bcol = bias[col];
      if (mode != 2) {
#pragma unroll
        for (int r = 0; r < 4; ++r) {
          int row = m0 + wm + mt * 16 + lg * 4 + r;
          out[(size_t)row * 1024 + col] = f2bf((acc[mt][nt][r] + bcol) * sc);
        }
      } else {
        int row0 = m0 + wm + mt * 16 + lg * 4;
        int b = row0 >> 9, n = row0 & 511;
        int h = col >> 6, d = col & 63;
        ushort4 pk;
        pk.x = f2bf(acc[mt][nt][0] + bcol);
        pk.y = f2bf(acc[mt][nt][1] + bcol);
        pk.z = f2bf(acc[mt][nt][2] + bcol);
        pk.w = f2bf(acc[mt][nt][3] + bcol);
        *reinterpret_cast<ushort4*>(out + ((size_t)(b * 16 + h) * 64 + d) * 512 + n) = pk;
      }
    }
  }
}

// ---------------------------------------------------------------------------
// K2: fused S1 GEMM + qt GEMM.
// y<16: S1[mrow][h][nsw] fp16 = qh.kh^T (128x128 tile, gll-staged, swizzled).
// y>=16: qt = qh(viewed [32768,64]) @ WrkB^T; slot handles 128 rows.
// ---------------------------------------------------------------------------
__global__ __launch_bounds__(256) void k_score1qt(
    const uint16_t* __restrict__ qh, const uint16_t* __restrict__ kh,
    const uint16_t* __restrict__ WrkB, uint16_t* __restrict__ S1,
    uint16_t* __restrict__ qt) {
  __shared__ alignas(16) uint16_t As[128 * 64];
  __shared__ alignas(16) uint16_t Bs[128 * 64];
  int t = threadIdx.x, lane = t & 63, w = t >> 6, lr = lane & 15, lg = lane >> 4;
  int b = blockIdx.z;
  if (blockIdx.y >= 16) {
    // ---- qt branch: slot in [0,256), 128 rows each
    int slot = (blockIdx.y - 16) * 64 + b * 16 + blockIdx.x;
#pragma unroll
    for (int it = 0; it < 2; ++it) {
      int row0 = slot * 128 + it * 64 + w * 16;
      f32x4 acc[8];
#pragma unroll
      for (int i = 0; i < 8; ++i) acc[i] = (f32x4){0.f, 0.f, 0.f, 0.f};
      s16x8 af[2];
#pragma unroll
      for (int kk = 0; kk < 2; ++kk)
        af[kk] = *(const s16x8*)(qh + (size_t)(row0 + lr) * 64 + kk * 32 + lg * 8);
#pragma unroll
      for (int rt = 0; rt < 8; ++rt) {
#pragma unroll
        for (int kk = 0; kk < 2; ++kk) {
          s16x8 bf = *(const s16x8*)(WrkB + (size_t)(rt * 16 + lr) * 64 + kk * 32 + lg * 8);
          acc[rt] = MFMA16(af[kk], bf, acc[rt]);
        }
      }
#pragma unroll
      for (int rt = 0; rt < 8; ++rt)
#pragma unroll
        for (int r = 0; r < 4; ++r)
          qt[(size_t)(row0 + lg * 4 + r) * 128 + rt * 16 + lr] = f2bf(acc[rt][r]);
    }
    return;
  }
  // ---- S1 branch
  int mt = blockIdx.x >> 2, nt = blockIdx.x & 3, h = blockIdx.y;
  int m0 = mt * 128, n0 = nt * 128;
  const char* qg = (const char*)(qh + (size_t)(b * 512 + m0) * 1024 + h * 64);
  const char* kg = (const char*)(kh + (size_t)(b * 512 + n0) * 1024 + h * 64);
#pragma unroll
  for (int i = 0; i < 4; ++i) {
    int u = i * 256 + t;
    int row = u >> 3;
    int cs = (u & 7) ^ (row & 7);
    gll16(qg + (size_t)row * 2048 + cs * 16, (char*)As + u * 16);
    gll16(kg + (size_t)row * 2048 + cs * 16, (char*)Bs + u * 16);
  }
  __syncthreads();
  int wm = (w >> 1) * 64, wn = (w & 1) * 64;
  f32x4 acc[4][4];
#pragma unroll
  for (int i = 0; i < 4; ++i)
#pragma unroll
    for (int j = 0; j < 4; ++j) acc[i][j] = (f32x4){0.f, 0.f, 0.f, 0.f};
#pragma unroll
  for (int kk = 0; kk < 2; ++kk) {
    s16x8 af[4], bf[4];
#pragma unroll
    for (int mtt = 0; mtt < 4; ++mtt) {
      int row = wm + mtt * 16 + lr;
      af[mtt] = *(const s16x8*)((const char*)As + row * 128 +
                                (((kk * 4 + lg) ^ (row & 7)) * 16));
    }
#pragma unroll
    for (int ntt = 0; ntt < 4; ++ntt) {
      int row = wn + ntt * 16 + lr;
      bf[ntt] = *(const s16x8*)((const char*)Bs + row * 128 +
                                (((kk * 4 + lg) ^ (row & 7)) * 16));
    }
#pragma unroll
    for (int mtt = 0; mtt < 4; ++mtt)
#pragma unroll
      for (int ntt = 0; ntt < 4; ++ntt)
        acc[mtt][ntt] = MFMA16(bf[ntt], af[mtt], acc[mtt][ntt]);
  }
  int hsw = (h & 7) << 3;
#pragma unroll
  for (int mtt = 0; mtt < 4; ++mtt) {
#pragma unroll
    for (int ntt = 0; ntt < 4; ++ntt) {
      int m = b * 512 + m0 + wm + mtt * 16 + lr;
      int nsw = (n0 + wn + ntt * 16 + lg * 4) ^ hsw;
      ushort4 u4;
      u4.x = f2h(acc[mtt][ntt][0]); u4.y = f2h(acc[mtt][ntt][1]);
      u4.z = f2h(acc[mtt][ntt][2]); u4.w = f2h(acc[mtt][ntt][3]);
      *(ushort4*)(S1 + (size_t)m * 8192 + h * 512 + nsw) = u4;
    }
  }
}

// ---------------------------------------------------------------------------
// K3: per-(b,m) relation streams. Wave-private gll pipelines, 4 blocks/CU.
// Issue order: aqt(4 loads), rk chunk0,1 (4 glls), S1 (4 glls), then chunks
// 2..31 issued inside RKSTEPs. vmcnt: s<2 -> 6, s<31 -> 2, s=31 -> 0.
// ---------------------------------------------------------------------------
#define RKSTEP(s)                                                              \
  {                                                                            \
    asm volatile("s_waitcnt vmcnt(%0)" ::                                      \
                 "i"(((s) < 2) ? 6 : (((s) < 31) ? 2 : 0)) : "memory");        \
    const char* bp_ = wpriv + ((s) & 1) * 2048 + lr * 128;                     \
    float4 v0_ = *(const float4*)(bp_ + (((lg * 2 + 0) ^ (lr & 7)) * 16));     \
    float4 v1_ = *(const float4*)(bp_ + (((lg * 2 + 1) ^ (lr & 7)) * 16));     \
    acc[(s) >> 2] = MFMA16(aqt[(s) & 3], pack8(v0_, v1_), acc[(s) >> 2]);      \
    if ((s) + 2 < 32) {                                                        \
      const int s2_ = (s) + 2;                                                 \
      const char* src_ = rkb + (size_t)((s2_ >> 2) * 64 + w * 16 + r_lo) * 512 \
                         + (s2_ & 3) * 128 + c16s * 16;                        \
      char* dst_ = wpriv + (s2_ & 1) * 2048 + lane * 16;                       \
      gll16(src_, dst_);                                                       \
      gll16(src_ + 8 * 512, dst_ + 1024);                                      \
    }                                                                          \
  }

#define RVI(c)                                                                 \
  { _Pragma("unroll")                                                          \
    for (int i_ = 0; i_ < 2; ++i_) {                                           \
      int u_ = i_ * 64 + lane;                                                 \
      gll16(rvb + (size_t)(((c) >> 1) * 32 + (u_ >> 2)) * 512 + w * 128 +      \
                ((c) & 1) * 64 + (u_ & 3) * 16,                                \
            wpriv + ((c) & 1) * 2048 + u_ * 16);                               \
    } }

#define RVC(c, accv)                                                           \
  {                                                                            \
    s16x8 a_ = *(const s16x8*)((const char*)att_lds + lr * 1024 +              \
        (((uint32_t)(((c) >> 1) * 64 + lg * 16)) ^ ((uint32_t)(lr & 7) << 4)));\
    const float* vb_ = (const float*)(wpriv + ((c) & 1) * 2048);               \
    union { uint32_t u[4]; s16x8 v; } bb_;                                     \
    _Pragma("unroll")                                                          \
    for (int i = 0; i < 4; ++i)                                                \
      bb_.u[i] = cvtpk(vb_[(lg * 8 + 2 * i) * 16 + lr],                        \
                       vb_[(lg * 8 + 2 * i + 1) * 16 + lr]);                   \
    accv = MFMA16(a_, bb_.v, accv);                                            \
  }

__global__ __launch_bounds__(256, 4) void k_s2v2(
    const uint16_t* __restrict__ qt, const float* __restrict__ rk,
    const float* __restrict__ rv, uint16_t* SATT,
    const uint16_t* __restrict__ WrvT, const float* __restrict__ brv,
    uint16_t* __restrict__ V2) {
  int bm = blockIdx.x;
  int t = threadIdx.x, lane = t & 63, w = t >> 6, lr = lane & 15, lg = lane >> 4;
  __shared__ alignas(16) char stream_lds[16384];      // 4KB per wave, private
  __shared__ alignas(16) uint16_t att_lds[16 * 512];  // S1 fp16 -> att bf16
  __shared__ alignas(16) uint16_t arv_lds[16 * 128];
  __shared__ float red[2][16][4];
  char* wpriv = stream_lds + w * 4096;
  const int r_lo = lane >> 3;               // 0..7
  const int c16s = (lane & 7) ^ r_lo;       // swizzled rk source chunk

  s16x8 aqt[4];
#pragma unroll
  for (int kk = 0; kk < 4; ++kk)
    aqt[kk] = *(const s16x8*)(qt + ((size_t)bm * 16 + lr) * 128 + kk * 32 + lg * 8);

  // rk prologue: chunks 0,1
  const char* rkb = (const char*)(rk + (size_t)bm * 65536);
#pragma unroll
  for (int s2 = 0; s2 < 2; ++s2) {
    const char* src_ = rkb + (size_t)(w * 16 + r_lo) * 512 + s2 * 128 + c16s * 16;
    char* dst_ = wpriv + s2 * 2048 + lane * 16;
    gll16(src_, dst_);
    gll16(src_ + 8 * 512, dst_ + 1024);
  }
  // S1 stage rides under the rk stream (counted in RKSTEP vmcnt)
  const char* s1g = (const char*)(SATT + (size_t)bm * 8192);
#pragma unroll
  for (int i = 0; i < 4; ++i)
    gll16(s1g + i * 4096 + t * 16, (char*)att_lds + i * 4096 + t * 16);

  f32x4 acc[8];
#pragma unroll
  for (int j = 0; j < 8; ++j) acc[j] = (f32x4){0.f, 0.f, 0.f, 0.f};

  RKSTEP(0)  RKSTEP(1)  RKSTEP(2)  RKSTEP(3)  RKSTEP(4)  RKSTEP(5)  RKSTEP(6)  RKSTEP(7)
  RKSTEP(8)  RKSTEP(9)  RKSTEP(10) RKSTEP(11) RKSTEP(12) RKSTEP(13) RKSTEP(14) RKSTEP(15)
  RKSTEP(16) RKSTEP(17) RKSTEP(18) RKSTEP(19) RKSTEP(20) RKSTEP(21) RKSTEP(22) RKSTEP(23)
  RKSTEP(24) RKSTEP(25) RKSTEP(26) RKSTEP(27) RKSTEP(28) RKSTEP(29) RKSTEP(30) RKSTEP(31)

  __syncthreads();  // S1 (all waves' quarters) visible; drains vmcnt

  // rv prefetch chunks 0,1: overlaps S1-add + softmax VALU below
  const char* rvb = (const char*)(rv + (size_t)bm * 65536);
  RVI(0) RVI(1)

  // ---- S1 add (fp16 from att_lds)
#pragma unroll
  for (int idx = 0; idx < 8; ++idx) {
#pragma unroll
    for (int r = 0; r < 4; ++r) {
      int h = lg * 4 + r;
      int n = idx * 64 + w * 16 + lr;
      uint16_t s1v = *(const uint16_t*)((const char*)att_lds + h * 1024 +
                     (((uint32_t)n * 2) ^ ((uint32_t)(h & 7) << 4)));
      acc[idx][r] += h2f(s1v);
    }
  }

  // ---- softmax
  float mrow[4], inv[4];
#pragma unroll
  for (int r = 0; r < 4; ++r) {
    float mx = acc[0][r];
#pragma unroll
    for (int j = 1; j < 8; ++j) mx = fmaxf(mx, acc[j][r]);
#pragma unroll
    for (int off = 1; off < 16; off <<= 1) mx = fmaxf(mx, __shfl_xor(mx, off, 64));
    mrow[r] = mx;
  }
  if (lr == 0) {
#pragma unroll
    for (int r = 0; r < 4; ++r) red[0][lg * 4 + r][w] = mrow[r];
  }
  __syncthreads();
#pragma unroll
  for (int r = 0; r < 4; ++r) {
    const float* p = red[0][lg * 4 + r];
    mrow[r] = fmaxf(fmaxf(p[0], p[1]), fmaxf(p[2], p[3]));
  }
#pragma unroll
  for (int r = 0; r < 4; ++r) {
    float s = 0.f;
#pragma unroll
    for (int j = 0; j < 8; ++j) {
      float pj = __expf(acc[j][r] - mrow[r]);
      acc[j][r] = pj;
      s += pj;
    }
#pragma unroll
    for (int off = 1; off < 16; off <<= 1) s += __shfl_xor(s, off, 64);
    inv[r] = s;
  }
  if (lr == 0) {
#pragma unroll
    for (int r = 0; r < 4; ++r) red[1][lg * 4 + r][w] = inv[r];
  }
  __syncthreads();
#pragma unroll
  for (int r = 0; r < 4; ++r) {
    const float* p = red[1][lg * 4 + r];
    inv[r] = 1.f / (p[0] + p[1] + p[2] + p[3]);
  }
#pragma unroll
  for (int r = 0; r < 4; ++r) {
    int h = lg * 4 + r;
#pragma unroll
    for (int idx = 0; idx < 8; ++idx) {
      int n = idx * 64 + w * 16 + lr;
      uint32_t off = (uint32_t)h * 1024 + (((uint32_t)n * 2) ^ ((uint32_t)(h & 7) << 4));
      *(uint16_t*)((char*)att_lds + off) = f2bf(acc[idx][r] * inv[r]);
    }
  }
  __syncthreads();  // att published (drains rv prefetch; chunks 0,1 in LDS)

  // ---- rv stream: 32 half-chunks, 2-deep
  f32x4 arv0 = (f32x4){0.f, 0.f, 0.f, 0.f}, arv1 = arv0;
#pragma unroll 1
  for (int cp = 0; cp < 14; ++cp) {
    asm volatile("s_waitcnt vmcnt(2)" ::: "memory");
    RVC(2 * cp, arv0)
    RVI(2 * cp + 2)
    asm volatile("s_waitcnt vmcnt(2)" ::: "memory");
    RVC(2 * cp + 1, arv1)
    RVI(2 * cp + 3)
  }
  asm volatile("s_waitcnt vmcnt(2)" ::: "memory");
  RVC(28, arv0)
  RVI(30)
  asm volatile("s_waitcnt vmcnt(2)" ::: "memory");
  RVC(29, arv1)
  RVI(31)
  asm volatile("s_waitcnt vmcnt(2)" ::: "memory");
  RVC(30, arv0)
  asm volatile("s_waitcnt vmcnt(0)" ::: "memory");
  RVC(31, arv1)

  // ---- arv -> LDS, val2 = arv @ Wrv + brv -> V2
#pragma unroll
  for (int r = 0; r < 4; ++r) {
    int h = lg * 4 + r;
    uint32_t rc0 = (uint32_t)(w * 32 + lr) * 2;
    uint32_t rc1 = (uint32_t)(w * 32 + 16 + lr) * 2;
    *(uint16_t*)((char*)arv_lds + h * 256 + (rc0 ^ ((uint32_t)(h & 7) << 4))) = f2bf(arv0[r]);
    *(uint16_t*)((char*)arv_lds + h * 256 + (rc1 ^ ((uint32_t)(h & 7) << 4))) = f2bf(arv1[r]);
  }
  __syncthreads();
  f32x4 vacc = (f32x4){0.f, 0.f, 0.f, 0.f};
#pragma unroll
  for (int kk = 0; kk < 4; ++kk) {
    uint32_t rb = (uint32_t)(kk * 32 + lg * 8) * 2;
    s16x8 a = *(const s16x8*)((const char*)arv_lds + lr * 256 +
                              (rb ^ ((uint32_t)(lr & 7) << 4)));
    s16x8 bfw = *(const s16x8*)(WrvT + (size_t)(w * 16 + lr) * 128 + kk * 32 + lg * 8);
    vacc = MFMA16(a, bfw, vacc);
  }
  float bias = brv[w * 16 + lr];
#pragma unroll
  for (int r = 0; r < 4; ++r)
    V2[(size_t)bm * 1024 + (lg * 4 + r) * 64 + w * 16 + lr] = f2bf(vacc[r] + bias);

  // ---- att (bf16) -> global, in place over S1 (fire-and-forget)
#pragma unroll
  for (int i = 0; i < 4; ++i) {
    s16x8 vv = *(const s16x8*)((const char*)att_lds + i * 4096 + t * 16);
    *(s16x8*)((char*)SATT + (size_t)bm * 16384 + i * 4096 + t * 16) = vv;
  }
}

// ---------------------------------------------------------------------------
// K4: val = att @ vh + V2 -> VALB. Grid (16: mt x dh, 16 h, 4 b).
// ---------------------------------------------------------------------------
__global__ __launch_bounds__(256) void k_val1(
    const uint16_t* __restrict__ vhT, const uint16_t* __restrict__ ATT,
    const uint16_t* __restrict__ V2, uint16_t* __restrict__ VALB) {
  int t = threadIdx.x, lane = t & 63, w = t >> 6, lr = lane & 15, lg = lane >> 4;
  int mt = blockIdx.x >> 1, dh = blockIdx.x & 1, h = blockIdx.y, b = blockIdx.z;
  int mb = mt * 64 + w * 16;
  const uint16_t* vrow = vhT + ((size_t)((b * 16 + h) * 64) + dh * 32 + lr) * 512 + lg * 8;
  const uint16_t* arow = ATT + (size_t)(b * 512 + mb + lr) * 8192 + h * 512;
  f32x4 acc[2];
#pragma unroll
  for (int j = 0; j < 2; ++j) acc[j] = (f32x4){0.f, 0.f, 0.f, 0.f};
#pragma unroll 4
  for (int kk = 0; kk < 16; ++kk) {
    int nsw = (kk * 32 + lg * 8) ^ ((h & 7) << 3);
    s16x8 a0 = *(const s16x8*)(arow + nsw);
#pragma unroll
    for (int dt = 0; dt < 2; ++dt) {
      s16x8 vf = *(const s16x8*)(vrow + (size_t)dt * 16 * 512 + kk * 32);
      acc[dt] = MFMA16(vf, a0, acc[dt]);
    }
  }
#pragma unroll
  for (int dt = 0; dt < 2; ++dt) {
    size_t adr = (size_t)(b * 512 + mb + lr) * 1024 + h * 64 + dh * 32 + dt * 16 + lg * 4;
    ushort4 v2v = *(const ushort4*)(V2 + adr);
    ushort4 o;
    o.x = f2bf(acc[dt][0] + bf2f(v2v.x));
    o.y = f2bf(acc[dt][1] + bf2f(v2v.y));
    o.z = f2bf(acc[dt][2] + bf2f(v2v.z));
    o.w = f2bf(acc[dt][3] + bf2f(v2v.w));
    *(ushort4*)(VALB + adr) = o;
  }
}

// ---------------------------------------------------------------------------
// K5: out = VAL @ Wo + bo; Bs staged via gll.
// ---------------------------------------------------------------------------
__global__ __launch_bounds__(256) void k_out(
    const uint16_t* __restrict__ A, const uint16_t* __restrict__ WT,
    const float* __restrict__ bias, float* __restrict__ out) {
  __shared__ alignas(16) uint16_t As[128 * 64];
  __shared__ alignas(16) uint16_t Bs[128 * 64];
  int t = threadIdx.x, lane = t & 63, w = t >> 6, lr = lane & 15, lg = lane >> 4;
  int m0 = blockIdx.x * 128, n0 = blockIdx.y * 128;
  int wm = (w >> 1) * 64, wn = (w & 1) * 64;
  f32x4 acc[4][4];
#pragma unroll
  for (int i = 0; i < 4; ++i)
#pragma unroll
    for (int j = 0; j < 4; ++j) acc[i][j] = (f32x4){0.f, 0.f, 0.f, 0.f};
  int srow = t >> 1, sh = t & 1;
  for (int ko = 0; ko < 16; ++ko) {
    __syncthreads();
    {
#pragma unroll
      for (int i = 0; i < 4; ++i) {
        int u = i * 256 + t;
        int row = u >> 3, c2 = u & 7;
        gll16(WT + (size_t)(n0 + row) * 1024 + ko * 64 + c2 * 8, (char*)Bs + u * 16);
      }
      const uint16_t* asrc = A + (size_t)(m0 + srow) * 1024 + ko * 64 + sh * 32;
#pragma unroll
      for (int c = 0; c < 4; ++c) {
        s16x8 va = *(const s16x8*)(asrc + c * 8);
        *reinterpret_cast<s16x8*>((char*)As + srow * 128 +
                                  ((((sh * 4 + c) * 16)) ^ ((srow & 7) << 4))) = va;
      }
    }
    __syncthreads();
#pragma unroll
    for (int kk = 0; kk < 2; ++kk) {
      s16x8 af[4], bf[4];
#pragma unroll
      for (int mt = 0; mt < 4; ++mt) {
        int row = wm + mt * 16 + lr;
        af[mt] = *(const s16x8*)((const char*)As + row * 128 +
                                 (((kk * 32 + lg * 8) * 2) ^ ((row & 7) << 4)));
      }
#pragma unroll
      for (int nt = 0; nt < 4; ++nt) {
        int row = wn + nt * 16 + lr;
        bf[nt] = *(const s16x8*)((const char*)Bs + row * 128 +
                                 (((kk * 32 + lg * 8) * 2) ^ ((row & 7) << 4)));
      }
#pragma unroll
      for (int mt = 0; mt < 4; ++mt)
#pragma unroll
        for (int nt = 0; nt < 4; ++nt)
          acc[mt][nt] = MFMA16(af[mt], bf[nt], acc[mt][nt]);
    }
  }
#pragma unroll
  for (int mt = 0; mt < 4; ++mt) {
#pragma unroll
    for (int nt = 0; nt < 4; ++nt) {
      int col = n0 + wn + nt * 16 + lr;
      float bcol = bias[col];
#pragma unroll
      for (int r = 0; r < 4; ++r) {
        int row = m0 + wm + mt * 16 + lg * 4 + r;
        out[(size_t)row * 1024 + col] = acc[mt][nt][r] + bcol;
      }
    }
  }
}

// ---------------------------------------------------------------------------
extern "C" void kernel_launch(void* const* d_in, const int* in_sizes, int n_in,
                              void* d_out, int out_size, void* d_ws, size_t ws_size,
                              hipStream_t stream) {
  const float* q   = (const float*)d_in[0];
  const float* k_  = (const float*)d_in[1];
  const float* v   = (const float*)d_in[2];
  const float* r_k = (const float*)d_in[3];
  const float* r_v = (const float*)d_in[4];
  const float* Wq  = (const float*)d_in[5];
  const float* bq  = (const float*)d_in[6];
  const float* Wk  = (const float*)d_in[7];
  const float* bk  = (const float*)d_in[8];
  const float* Wv  = (const float*)d_in[9];
  const float* bv  = (const float*)d_in[10];
  const float* Wrk = (const float*)d_in[11];
  // d_in[12] = brk: softmax-invariant, unused
  const float* Wrv = (const float*)d_in[13];
  const float* brv = (const float*)d_in[14];
  const float* Wo  = (const float*)d_in[15];
  const float* bo  = (const float*)d_in[16];
  (void)in_sizes; (void)n_in; (void)out_size;

  char* ws = (char*)d_ws;
  uint16_t* WqT  = (uint16_t*)(ws + (size_t)(0));
  uint16_t* WkT  = (uint16_t*)(ws + (size_t)(2u << 20));
  uint16_t* WvT  = (uint16_t*)(ws + (size_t)(4u << 20));
  uint16_t* WoT  = (uint16_t*)(ws + (size_t)(6u << 20));
  uint16_t* WrkB = (uint16_t*)(ws + (size_t)(8u << 20));
  uint16_t* WrvT = (uint16_t*)(ws + (size_t)(8u << 20) + (64u << 10));
  uint16_t* QH   = (uint16_t*)(ws + (size_t)(16u << 20));
  uint16_t* KH   = (uint16_t*)(ws + (size_t)(20u << 20));
  uint16_t* VHT  = (uint16_t*)(ws + (size_t)(24u << 20));
  uint16_t* QT   = (uint16_t*)(ws + (size_t)(28u << 20));
  uint16_t* VALB = (uint16_t*)(ws + (size_t)(36u << 20));
  uint16_t* V2   = (uint16_t*)(ws + (size_t)(16u << 20));  // QH slot, dead after score1
  uint16_t* SATT = (uint16_t*)(ws + (size_t)(40u << 20));  // 33.6 MB
  if (ws_size < (size_t)(74u << 20)) return;  // need 74 MB of scratch

  dim3 blk(256, 1, 1);
  k_prep<<<dim3(256, 5, 1), blk, 0, stream>>>(Wq, Wk, Wv, Wo, Wrk, Wrv,
                                              WqT, WkT, WvT, WoT, WrkB, WrvT);
  k_projqkv<<<dim3(16, 8, 3), blk, 0, stream>>>(q, k_, v, WqT, bq, bk, bv, QH);
  k_score1qt<<<dim3(16, 20, 4), blk, 0, stream>>>(QH, KH, WrkB, SATT, QT);
  k_s2v2<<<dim3(2048, 1, 1), blk, 0, stream>>>(QT, r_k, r_v, SATT, WrvT, brv, V2);
  k_val1<<<dim3(16, 16, 4), blk, 0, stream>>>(VHT, SATT, V2, VALB);
  k_out<<<dim3(16, 8, 1), blk, 0, stream>>>(VALB, WoT, bo, (float*)d_out);
}

// Round 8
// 344.924 us; speedup vs baseline: 1.1088x; 1.0794x over previous
//
#include <hip/hip_runtime.h>
#include <hip/hip_bf16.h>
#include <hip/hip_fp16.h>
#include <stdint.h>

// RelationMultiHeadAttention on MI355X.
// R8: gll-staged A-operands in k_projqkv (fp32, swizzled) and k_out (bf16,
// pre-swizzled source); k_val1 fully unrolled with VGPR headroom.
// Pipeline: k_prep -> k_projqkv -> k_score1qt -> k_s2v2 -> k_val1 -> k_out

typedef __attribute__((ext_vector_type(4))) float f32x4;
typedef __attribute__((ext_vector_type(8))) short s16x8;

#define MFMA16(A, B, C) __builtin_amdgcn_mfma_f32_16x16x32_bf16(A, B, C, 0, 0, 0)

__device__ __forceinline__ uint16_t f2bf(float x) {
  uint32_t u = __float_as_uint(x);
  u += 0x7fffu + ((u >> 16) & 1u);
  return (uint16_t)(u >> 16);
}
__device__ __forceinline__ float bf2f(uint16_t u) {
  return __uint_as_float((uint32_t)u << 16);
}
__device__ __forceinline__ uint16_t f2h(float x) {
  __half h = __float2half_rn(x);
  return *reinterpret_cast<uint16_t*>(&h);
}
__device__ __forceinline__ float h2f(uint16_t u) {
  __half h = *reinterpret_cast<__half*>(&u);
  return __half2float(h);
}

// v_cvt_pk_bf16_f32: two f32 -> packed 2x bf16 (RNE), 1 VALU op per pair.
__device__ __forceinline__ uint32_t cvtpk(float lo, float hi) {
  uint32_t r;
  asm("v_cvt_pk_bf16_f32 %0, %1, %2" : "=v"(r) : "v"(lo), "v"(hi));
  return r;
}

__device__ __forceinline__ s16x8 pack8(float4 a, float4 b) {
  union { uint32_t u[4]; s16x8 v; } r;
  r.u[0] = cvtpk(a.x, a.y);
  r.u[1] = cvtpk(a.z, a.w);
  r.u[2] = cvtpk(b.x, b.y);
  r.u[3] = cvtpk(b.z, b.w);
  return r.v;
}

__device__ __forceinline__ void gll16(const void* g, void* l) {
  __builtin_amdgcn_global_load_lds(
      (const __attribute__((address_space(1))) uint32_t*)(g),
      (__attribute__((address_space(3))) uint32_t*)(l), 16, 0, 0);
}

// ---------------------------------------------------------------------------
// K0: weight prep (unchanged).
// ---------------------------------------------------------------------------
__global__ __launch_bounds__(256) void k_prep(
    const float* __restrict__ Wq, const float* __restrict__ Wk,
    const float* __restrict__ Wv, const float* __restrict__ Wo,
    const float* __restrict__ Wrk, const float* __restrict__ Wrv,
    uint16_t* __restrict__ WqT, uint16_t* __restrict__ WkT,
    uint16_t* __restrict__ WvT, uint16_t* __restrict__ WoT,
    uint16_t* __restrict__ WrkB, uint16_t* __restrict__ WrvT) {
  int z = blockIdx.y;
  int t = threadIdx.x;
  if (z == 4) {
    if (blockIdx.x == 0) {
      for (int i = t; i < 128 * 64; i += 256) WrkB[i] = f2bf(Wrk[i]);
      for (int i = t; i < 64 * 128; i += 256) {
        int d = i >> 7, r = i & 127;
        WrvT[i] = f2bf(Wrv[r * 64 + d]);
      }
    }
    return;
  }
  const float* W = (z == 0) ? Wq : (z == 1) ? Wk : (z == 2) ? Wv : Wo;
  uint16_t* O = (z == 0) ? WqT : (z == 1) ? WkT : (z == 2) ? WvT : WoT;
  int tk = (blockIdx.x >> 4) * 64;
  int tn = (blockIdx.x & 15) * 64;
  __shared__ float tile[64][65];
  {
    int kk = t >> 2, c0 = (t & 3) * 16;
    const float* src = W + (size_t)(tk + kk) * 1024 + tn + c0;
#pragma unroll
    for (int i = 0; i < 16; i += 4) {
      float4 v = *(const float4*)(src + i);
      tile[kk][c0 + i + 0] = v.x; tile[kk][c0 + i + 1] = v.y;
      tile[kk][c0 + i + 2] = v.z; tile[kk][c0 + i + 3] = v.w;
    }
  }
  __syncthreads();
  {
    int n_loc = t >> 2;
    int n = tn + n_loc;
#pragma unroll
    for (int cc = 0; cc < 2; ++cc) {
      int c = (t & 3) * 2 + cc;
      int csrc = c ^ (n & 7);
      s16x8 pk;
#pragma unroll
      for (int j = 0; j < 8; ++j) pk[j] = (short)f2bf(tile[csrc * 8 + j][n_loc]);
      *reinterpret_cast<s16x8*>(O + (size_t)n * 1024 + tk + c * 8) = pk;
    }
  }
}

// ---------------------------------------------------------------------------
// K1: projections. A staged fp32 via gll (src pre-swizzled, chunk ^= row&15),
// cvt_pk applied at frag read. Bs via gll (WT pre-swizzled).
// ---------------------------------------------------------------------------
__global__ __launch_bounds__(256) void k_projqkv(
    const float* __restrict__ Xq, const float* __restrict__ Xk,
    const float* __restrict__ Xv, const uint16_t* __restrict__ WTbase,
    const float* __restrict__ bq, const float* __restrict__ bk,
    const float* __restrict__ bv, uint16_t* __restrict__ outbase) {
  int mode = blockIdx.z;
  const float* X = (mode == 0) ? Xq : (mode == 1) ? Xk : Xv;
  const float* bias = (mode == 0) ? bq : (mode == 1) ? bk : bv;
  const uint16_t* WT = WTbase + (size_t)mode * (1u << 20);
  uint16_t* out = outbase + (size_t)mode * (2u << 20);

  __shared__ alignas(16) float Xs[128 * 64];       // 32KB fp32 A tile (swizzled)
  __shared__ alignas(16) uint16_t Bs[128 * 64];    // 16KB
  int t = threadIdx.x, lane = t & 63, w = t >> 6, lr = lane & 15, lg = lane >> 4;
  int m0 = blockIdx.x * 128, n0 = blockIdx.y * 128;
  int wm = (w >> 1) * 64, wn = (w & 1) * 64;
  f32x4 acc[4][4];
#pragma unroll
  for (int i = 0; i < 4; ++i)
#pragma unroll
    for (int j = 0; j < 4; ++j) acc[i][j] = (f32x4){0.f, 0.f, 0.f, 0.f};
  for (int ko = 0; ko < 16; ++ko) {
    __syncthreads();
    {
      // X fp32 tile: rows 128 x 256B (16 chunks); LDS[row][c] = glob[row][c^(row&15)]
#pragma unroll
      for (int i = 0; i < 8; ++i) {
        int u = i * 256 + t;
        int row = u >> 4, c16 = u & 15;
        int cs = c16 ^ (row & 15);
        gll16(X + (size_t)(m0 + row) * 1024 + ko * 64 + cs * 4, (char*)Xs + u * 16);
      }
#pragma unroll
      for (int i = 0; i < 4; ++i) {
        int u = i * 256 + t;
        int row = u >> 3, c2 = u & 7;
        gll16(WT + (size_t)(n0 + row) * 1024 + ko * 64 + c2 * 8, (char*)Bs + u * 16);
      }
    }
    __syncthreads();
#pragma unroll
    for (int kk = 0; kk < 2; ++kk) {
      s16x8 af[4], bf[4];
#pragma unroll
      for (int mt = 0; mt < 4; ++mt) {
        int row = wm + mt * 16 + lr;
        int c0 = kk * 8 + lg * 2;  // fp32 chunk base (32B = 2 chunks)
        float4 v0 = *(const float4*)((const char*)Xs + row * 256 +
                                     ((c0 ^ (row & 15)) * 16));
        float4 v1 = *(const float4*)((const char*)Xs + row * 256 +
                                     (((c0 + 1) ^ (row & 15)) * 16));
        af[mt] = pack8(v0, v1);
      }
#pragma unroll
      for (int nt = 0; nt < 4; ++nt) {
        int row = wn + nt * 16 + lr;
        bf[nt] = *(const s16x8*)((const char*)Bs + row * 128 +
                                 (((kk * 32 + lg * 8) * 2) ^ ((row & 7) << 4)));
      }
#pragma unroll
      for (int mt = 0; mt < 4; ++mt)
#pragma unroll
        for (int nt = 0; nt < 4; ++nt)
          acc[mt][nt] = MFMA16(af[mt], bf[nt], acc[mt][nt]);
    }
  }
  float sc = (mode == 1) ? 0.125f : 1.0f;
#pragma unroll
  for (int mt = 0; mt < 4; ++mt) {
#pragma unroll
    for (int nt = 0; nt < 4; ++nt) {
      int col = n0 + wn + nt * 16 + lr;
      float bcol = bias[col];
      if (mode != 2) {
#pragma unroll
        for (int r = 0; r < 4; ++r) {
          int row = m0 + wm + mt * 16 + lg * 4 + r;
          out[(size_t)row * 1024 + col] = f2bf((acc[mt][nt][r] + bcol) * sc);
        }
      } else {
        int row0 = m0 + wm + mt * 16 + lg * 4;
        int b = row0 >> 9, n = row0 & 511;
        int h = col >> 6, d = col & 63;
        ushort4 pk;
        pk.x = f2bf(acc[mt][nt][0] + bcol);
        pk.y = f2bf(acc[mt][nt][1] + bcol);
        pk.z = f2bf(acc[mt][nt][2] + bcol);
        pk.w = f2bf(acc[mt][nt][3] + bcol);
        *reinterpret_cast<ushort4*>(out + ((size_t)(b * 16 + h) * 64 + d) * 512 + n) = pk;
      }
    }
  }
}

// ---------------------------------------------------------------------------
// K2: fused S1 GEMM + qt GEMM (unchanged).
// ---------------------------------------------------------------------------
__global__ __launch_bounds__(256) void k_score1qt(
    const uint16_t* __restrict__ qh, const uint16_t* __restrict__ kh,
    const uint16_t* __restrict__ WrkB, uint16_t* __restrict__ S1,
    uint16_t* __restrict__ qt) {
  __shared__ alignas(16) uint16_t As[128 * 64];
  __shared__ alignas(16) uint16_t Bs[128 * 64];
  int t = threadIdx.x, lane = t & 63, w = t >> 6, lr = lane & 15, lg = lane >> 4;
  int b = blockIdx.z;
  if (blockIdx.y >= 16) {
    int slot = (blockIdx.y - 16) * 64 + b * 16 + blockIdx.x;
#pragma unroll
    for (int it = 0; it < 2; ++it) {
      int row0 = slot * 128 + it * 64 + w * 16;
      f32x4 acc[8];
#pragma unroll
      for (int i = 0; i < 8; ++i) acc[i] = (f32x4){0.f, 0.f, 0.f, 0.f};
      s16x8 af[2];
#pragma unroll
      for (int kk = 0; kk < 2; ++kk)
        af[kk] = *(const s16x8*)(qh + (size_t)(row0 + lr) * 64 + kk * 32 + lg * 8);
#pragma unroll
      for (int rt = 0; rt < 8; ++rt) {
#pragma unroll
        for (int kk = 0; kk < 2; ++kk) {
          s16x8 bf = *(const s16x8*)(WrkB + (size_t)(rt * 16 + lr) * 64 + kk * 32 + lg * 8);
          acc[rt] = MFMA16(af[kk], bf, acc[rt]);
        }
      }
#pragma unroll
      for (int rt = 0; rt < 8; ++rt)
#pragma unroll
        for (int r = 0; r < 4; ++r)
          qt[(size_t)(row0 + lg * 4 + r) * 128 + rt * 16 + lr] = f2bf(acc[rt][r]);
    }
    return;
  }
  int mt = blockIdx.x >> 2, nt = blockIdx.x & 3, h = blockIdx.y;
  int m0 = mt * 128, n0 = nt * 128;
  const char* qg = (const char*)(qh + (size_t)(b * 512 + m0) * 1024 + h * 64);
  const char* kg = (const char*)(kh + (size_t)(b * 512 + n0) * 1024 + h * 64);
#pragma unroll
  for (int i = 0; i < 4; ++i) {
    int u = i * 256 + t;
    int row = u >> 3;
    int cs = (u & 7) ^ (row & 7);
    gll16(qg + (size_t)row * 2048 + cs * 16, (char*)As + u * 16);
    gll16(kg + (size_t)row * 2048 + cs * 16, (char*)Bs + u * 16);
  }
  __syncthreads();
  int wm = (w >> 1) * 64, wn = (w & 1) * 64;
  f32x4 acc[4][4];
#pragma unroll
  for (int i = 0; i < 4; ++i)
#pragma unroll
    for (int j = 0; j < 4; ++j) acc[i][j] = (f32x4){0.f, 0.f, 0.f, 0.f};
#pragma unroll
  for (int kk = 0; kk < 2; ++kk) {
    s16x8 af[4], bf[4];
#pragma unroll
    for (int mtt = 0; mtt < 4; ++mtt) {
      int row = wm + mtt * 16 + lr;
      af[mtt] = *(const s16x8*)((const char*)As + row * 128 +
                                (((kk * 4 + lg) ^ (row & 7)) * 16));
    }
#pragma unroll
    for (int ntt = 0; ntt < 4; ++ntt) {
      int row = wn + ntt * 16 + lr;
      bf[ntt] = *(const s16x8*)((const char*)Bs + row * 128 +
                                (((kk * 4 + lg) ^ (row & 7)) * 16));
    }
#pragma unroll
    for (int mtt = 0; mtt < 4; ++mtt)
#pragma unroll
      for (int ntt = 0; ntt < 4; ++ntt)
        acc[mtt][ntt] = MFMA16(bf[ntt], af[mtt], acc[mtt][ntt]);
  }
  int hsw = (h & 7) << 3;
#pragma unroll
  for (int mtt = 0; mtt < 4; ++mtt) {
#pragma unroll
    for (int ntt = 0; ntt < 4; ++ntt) {
      int m = b * 512 + m0 + wm + mtt * 16 + lr;
      int nsw = (n0 + wn + ntt * 16 + lg * 4) ^ hsw;
      ushort4 u4;
      u4.x = f2h(acc[mtt][ntt][0]); u4.y = f2h(acc[mtt][ntt][1]);
      u4.z = f2h(acc[mtt][ntt][2]); u4.w = f2h(acc[mtt][ntt][3]);
      *(ushort4*)(S1 + (size_t)m * 8192 + h * 512 + nsw) = u4;
    }
  }
}

// ---------------------------------------------------------------------------
// K3: per-(b,m) relation streams (unchanged from R7).
// ---------------------------------------------------------------------------
#define RKSTEP(s)                                                              \
  {                                                                            \
    asm volatile("s_waitcnt vmcnt(%0)" ::                                      \
                 "i"(((s) < 2) ? 6 : (((s) < 31) ? 2 : 0)) : "memory");        \
    const char* bp_ = wpriv + ((s) & 1) * 2048 + lr * 128;                     \
    float4 v0_ = *(const float4*)(bp_ + (((lg * 2 + 0) ^ (lr & 7)) * 16));     \
    float4 v1_ = *(const float4*)(bp_ + (((lg * 2 + 1) ^ (lr & 7)) * 16));     \
    acc[(s) >> 2] = MFMA16(aqt[(s) & 3], pack8(v0_, v1_), acc[(s) >> 2]);      \
    if ((s) + 2 < 32) {                                                        \
      const int s2_ = (s) + 2;                                                 \
      const char* src_ = rkb + (size_t)((s2_ >> 2) * 64 + w * 16 + r_lo) * 512 \
                         + (s2_ & 3) * 128 + c16s * 16;                        \
      char* dst_ = wpriv + (s2_ & 1) * 2048 + lane * 16;                       \
      gll16(src_, dst_);                                                       \
      gll16(src_ + 8 * 512, dst_ + 1024);                                      \
    }                                                                          \
  }

#define RVI(c)                                                                 \
  { _Pragma("unroll")                                                          \
    for (int i_ = 0; i_ < 2; ++i_) {                                           \
      int u_ = i_ * 64 + lane;                                                 \
      gll16(rvb + (size_t)(((c) >> 1) * 32 + (u_ >> 2)) * 512 + w * 128 +      \
                ((c) & 1) * 64 + (u_ & 3) * 16,                                \
            wpriv + ((c) & 1) * 2048 + u_ * 16);                               \
    } }

#define RVC(c, accv)                                                           \
  {                                                                            \
    s16x8 a_ = *(const s16x8*)((const char*)att_lds + lr * 1024 +              \
        (((uint32_t)(((c) >> 1) * 64 + lg * 16)) ^ ((uint32_t)(lr & 7) << 4)));\
    const float* vb_ = (const float*)(wpriv + ((c) & 1) * 2048);               \
    union { uint32_t u[4]; s16x8 v; } bb_;                                     \
    _Pragma("unroll")                                                          \
    for (int i = 0; i < 4; ++i)                                                \
      bb_.u[i] = cvtpk(vb_[(lg * 8 + 2 * i) * 16 + lr],                        \
                       vb_[(lg * 8 + 2 * i + 1) * 16 + lr]);                   \
    accv = MFMA16(a_, bb_.v, accv);                                            \
  }

__global__ __launch_bounds__(256, 4) void k_s2v2(
    const uint16_t* __restrict__ qt, const float* __restrict__ rk,
    const float* __restrict__ rv, uint16_t* SATT,
    const uint16_t* __restrict__ WrvT, const float* __restrict__ brv,
    uint16_t* __restrict__ V2) {
  int bm = blockIdx.x;
  int t = threadIdx.x, lane = t & 63, w = t >> 6, lr = lane & 15, lg = lane >> 4;
  __shared__ alignas(16) char stream_lds[16384];
  __shared__ alignas(16) uint16_t att_lds[16 * 512];
  __shared__ alignas(16) uint16_t arv_lds[16 * 128];
  __shared__ float red[2][16][4];
  char* wpriv = stream_lds + w * 4096;
  const int r_lo = lane >> 3;
  const int c16s = (lane & 7) ^ r_lo;

  s16x8 aqt[4];
#pragma unroll
  for (int kk = 0; kk < 4; ++kk)
    aqt[kk] = *(const s16x8*)(qt + ((size_t)bm * 16 + lr) * 128 + kk * 32 + lg * 8);

  const char* rkb = (const char*)(rk + (size_t)bm * 65536);
#pragma unroll
  for (int s2 = 0; s2 < 2; ++s2) {
    const char* src_ = rkb + (size_t)(w * 16 + r_lo) * 512 + s2 * 128 + c16s * 16;
    char* dst_ = wpriv + s2 * 2048 + lane * 16;
    gll16(src_, dst_);
    gll16(src_ + 8 * 512, dst_ + 1024);
  }
  const char* s1g = (const char*)(SATT + (size_t)bm * 8192);
#pragma unroll
  for (int i = 0; i < 4; ++i)
    gll16(s1g + i * 4096 + t * 16, (char*)att_lds + i * 4096 + t * 16);

  f32x4 acc[8];
#pragma unroll
  for (int j = 0; j < 8; ++j) acc[j] = (f32x4){0.f, 0.f, 0.f, 0.f};

  RKSTEP(0)  RKSTEP(1)  RKSTEP(2)  RKSTEP(3)  RKSTEP(4)  RKSTEP(5)  RKSTEP(6)  RKSTEP(7)
  RKSTEP(8)  RKSTEP(9)  RKSTEP(10) RKSTEP(11) RKSTEP(12) RKSTEP(13) RKSTEP(14) RKSTEP(15)
  RKSTEP(16) RKSTEP(17) RKSTEP(18) RKSTEP(19) RKSTEP(20) RKSTEP(21) RKSTEP(22) RKSTEP(23)
  RKSTEP(24) RKSTEP(25) RKSTEP(26) RKSTEP(27) RKSTEP(28) RKSTEP(29) RKSTEP(30) RKSTEP(31)

  __syncthreads();

  const char* rvb = (const char*)(rv + (size_t)bm * 65536);
  RVI(0) RVI(1)

#pragma unroll
  for (int idx = 0; idx < 8; ++idx) {
#pragma unroll
    for (int r = 0; r < 4; ++r) {
      int h = lg * 4 + r;
      int n = idx * 64 + w * 16 + lr;
      uint16_t s1v = *(const uint16_t*)((const char*)att_lds + h * 1024 +
                     (((uint32_t)n * 2) ^ ((uint32_t)(h & 7) << 4)));
      acc[idx][r] += h2f(s1v);
    }
  }

  float mrow[4], inv[4];
#pragma unroll
  for (int r = 0; r < 4; ++r) {
    float mx = acc[0][r];
#pragma unroll
    for (int j = 1; j < 8; ++j) mx = fmaxf(mx, acc[j][r]);
#pragma unroll
    for (int off = 1; off < 16; off <<= 1) mx = fmaxf(mx, __shfl_xor(mx, off, 64));
    mrow[r] = mx;
  }
  if (lr == 0) {
#pragma unroll
    for (int r = 0; r < 4; ++r) red[0][lg * 4 + r][w] = mrow[r];
  }
  __syncthreads();
#pragma unroll
  for (int r = 0; r < 4; ++r) {
    const float* p = red[0][lg * 4 + r];
    mrow[r] = fmaxf(fmaxf(p[0], p[1]), fmaxf(p[2], p[3]));
  }
#pragma unroll
  for (int r = 0; r < 4; ++r) {
    float s = 0.f;
#pragma unroll
    for (int j = 0; j < 8; ++j) {
      float pj = __expf(acc[j][r] - mrow[r]);
      acc[j][r] = pj;
      s += pj;
    }
#pragma unroll
    for (int off = 1; off < 16; off <<= 1) s += __shfl_xor(s, off, 64);
    inv[r] = s;
  }
  if (lr == 0) {
#pragma unroll
    for (int r = 0; r < 4; ++r) red[1][lg * 4 + r][w] = inv[r];
  }
  __syncthreads();
#pragma unroll
  for (int r = 0; r < 4; ++r) {
    const float* p = red[1][lg * 4 + r];
    inv[r] = 1.f / (p[0] + p[1] + p[2] + p[3]);
  }
#pragma unroll
  for (int r = 0; r < 4; ++r) {
    int h = lg * 4 + r;
#pragma unroll
    for (int idx = 0; idx < 8; ++idx) {
      int n = idx * 64 + w * 16 + lr;
      uint32_t off = (uint32_t)h * 1024 + (((uint32_t)n * 2) ^ ((uint32_t)(h & 7) << 4));
      *(uint16_t*)((char*)att_lds + off) = f2bf(acc[idx][r] * inv[r]);
    }
  }
  __syncthreads();

  f32x4 arv0 = (f32x4){0.f, 0.f, 0.f, 0.f}, arv1 = arv0;
#pragma unroll 1
  for (int cp = 0; cp < 14; ++cp) {
    asm volatile("s_waitcnt vmcnt(2)" ::: "memory");
    RVC(2 * cp, arv0)
    RVI(2 * cp + 2)
    asm volatile("s_waitcnt vmcnt(2)" ::: "memory");
    RVC(2 * cp + 1, arv1)
    RVI(2 * cp + 3)
  }
  asm volatile("s_waitcnt vmcnt(2)" ::: "memory");
  RVC(28, arv0)
  RVI(30)
  asm volatile("s_waitcnt vmcnt(2)" ::: "memory");
  RVC(29, arv1)
  RVI(31)
  asm volatile("s_waitcnt vmcnt(2)" ::: "memory");
  RVC(30, arv0)
  asm volatile("s_waitcnt vmcnt(0)" ::: "memory");
  RVC(31, arv1)

#pragma unroll
  for (int r = 0; r < 4; ++r) {
    int h = lg * 4 + r;
    uint32_t rc0 = (uint32_t)(w * 32 + lr) * 2;
    uint32_t rc1 = (uint32_t)(w * 32 + 16 + lr) * 2;
    *(uint16_t*)((char*)arv_lds + h * 256 + (rc0 ^ ((uint32_t)(h & 7) << 4))) = f2bf(arv0[r]);
    *(uint16_t*)((char*)arv_lds + h * 256 + (rc1 ^ ((uint32_t)(h & 7) << 4))) = f2bf(arv1[r]);
  }
  __syncthreads();
  f32x4 vacc = (f32x4){0.f, 0.f, 0.f, 0.f};
#pragma unroll
  for (int kk = 0; kk < 4; ++kk) {
    uint32_t rb = (uint32_t)(kk * 32 + lg * 8) * 2;
    s16x8 a = *(const s16x8*)((const char*)arv_lds + lr * 256 +
                              (rb ^ ((uint32_t)(lr & 7) << 4)));
    s16x8 bfw = *(const s16x8*)(WrvT + (size_t)(w * 16 + lr) * 128 + kk * 32 + lg * 8);
    vacc = MFMA16(a, bfw, vacc);
  }
  float bias = brv[w * 16 + lr];
#pragma unroll
  for (int r = 0; r < 4; ++r)
    V2[(size_t)bm * 1024 + (lg * 4 + r) * 64 + w * 16 + lr] = f2bf(vacc[r] + bias);

#pragma unroll
  for (int i = 0; i < 4; ++i) {
    s16x8 vv = *(const s16x8*)((const char*)att_lds + i * 4096 + t * 16);
    *(s16x8*)((char*)SATT + (size_t)bm * 16384 + i * 4096 + t * 16) = vv;
  }
}

// ---------------------------------------------------------------------------
// K4: val = att @ vh + V2 -> VALB. Fully unrolled, VGPR cap 128.
// ---------------------------------------------------------------------------
__global__ __launch_bounds__(256, 4) void k_val1(
    const uint16_t* __restrict__ vhT, const uint16_t* __restrict__ ATT,
    const uint16_t* __restrict__ V2, uint16_t* __restrict__ VALB) {
  int t = threadIdx.x, lane = t & 63, w = t >> 6, lr = lane & 15, lg = lane >> 4;
  int mt = blockIdx.x >> 1, dh = blockIdx.x & 1, h = blockIdx.y, b = blockIdx.z;
  int mb = mt * 64 + w * 16;
  const uint16_t* vrow = vhT + ((size_t)((b * 16 + h) * 64) + dh * 32 + lr) * 512 + lg * 8;
  const uint16_t* arow = ATT + (size_t)(b * 512 + mb + lr) * 8192 + h * 512;
  f32x4 acc[2];
#pragma unroll
  for (int j = 0; j < 2; ++j) acc[j] = (f32x4){0.f, 0.f, 0.f, 0.f};
#pragma unroll
  for (int kk = 0; kk < 16; ++kk) {
    int nsw = (kk * 32 + lg * 8) ^ ((h & 7) << 3);
    s16x8 a0 = *(const s16x8*)(arow + nsw);
#pragma unroll
    for (int dt = 0; dt < 2; ++dt) {
      s16x8 vf = *(const s16x8*)(vrow + (size_t)dt * 16 * 512 + kk * 32);
      acc[dt] = MFMA16(vf, a0, acc[dt]);
    }
  }
#pragma unroll
  for (int dt = 0; dt < 2; ++dt) {
    size_t adr = (size_t)(b * 512 + mb + lr) * 1024 + h * 64 + dh * 32 + dt * 16 + lg * 4;
    ushort4 v2v = *(const ushort4*)(V2 + adr);
    ushort4 o;
    o.x = f2bf(acc[dt][0] + bf2f(v2v.x));
    o.y = f2bf(acc[dt][1] + bf2f(v2v.y));
    o.z = f2bf(acc[dt][2] + bf2f(v2v.z));
    o.w = f2bf(acc[dt][3] + bf2f(v2v.w));
    *(ushort4*)(VALB + adr) = o;
  }
}

// ---------------------------------------------------------------------------
// K5: out = VAL @ Wo + bo; both operands staged via gll (A src pre-swizzled).
// ---------------------------------------------------------------------------
__global__ __launch_bounds__(256) void k_out(
    const uint16_t* __restrict__ A, const uint16_t* __restrict__ WT,
    const float* __restrict__ bias, float* __restrict__ out) {
  __shared__ alignas(16) uint16_t As[128 * 64];
  __shared__ alignas(16) uint16_t Bs[128 * 64];
  int t = threadIdx.x, lane = t & 63, w = t >> 6, lr = lane & 15, lg = lane >> 4;
  int m0 = blockIdx.x * 128, n0 = blockIdx.y * 128;
  int wm = (w >> 1) * 64, wn = (w & 1) * 64;
  f32x4 acc[4][4];
#pragma unroll
  for (int i = 0; i < 4; ++i)
#pragma unroll
    for (int j = 0; j < 4; ++j) acc[i][j] = (f32x4){0.f, 0.f, 0.f, 0.f};
  for (int ko = 0; ko < 16; ++ko) {
    __syncthreads();
    {
#pragma unroll
      for (int i = 0; i < 4; ++i) {
        int u = i * 256 + t;
        int row = u >> 3, c2 = u & 7;
        int cs = c2 ^ (row & 7);  // A source pre-swizzle
        gll16(A + (size_t)(m0 + row) * 1024 + ko * 64 + cs * 8, (char*)As + u * 16);
        gll16(WT + (size_t)(n0 + row) * 1024 + ko * 64 + c2 * 8, (char*)Bs + u * 16);
      }
    }
    __syncthreads();
#pragma unroll
    for (int kk = 0; kk < 2; ++kk) {
      s16x8 af[4], bf[4];
#pragma unroll
      for (int mt = 0; mt < 4; ++mt) {
        int row = wm + mt * 16 + lr;
        af[mt] = *(const s16x8*)((const char*)As + row * 128 +
                                 (((kk * 32 + lg * 8) * 2) ^ ((row & 7) << 4)));
      }
#pragma unroll
      for (int nt = 0; nt < 4; ++nt) {
        int row = wn + nt * 16 + lr;
        bf[nt] = *(const s16x8*)((const char*)Bs + row * 128 +
                                 (((kk * 32 + lg * 8) * 2) ^ ((row & 7) << 4)));
      }
#pragma unroll
      for (int mt = 0; mt < 4; ++mt)
#pragma unroll
        for (int nt = 0; nt < 4; ++nt)
          acc[mt][nt] = MFMA16(af[mt], bf[nt], acc[mt][nt]);
    }
  }
#pragma unroll
  for (int mt = 0; mt < 4; ++mt) {
#pragma unroll
    for (int nt = 0; nt < 4; ++nt) {
      int col = n0 + wn + nt * 16 + lr;
      float bcol = bias[col];
#pragma unroll
      for (int r = 0; r < 4; ++r) {
        int row = m0 + wm + mt * 16 + lg * 4 + r;
        out[(size_t)row * 1024 + col] = acc[mt][nt][r] + bcol;
      }
    }
  }
}

// ---------------------------------------------------------------------------
extern "C" void kernel_launch(void* const* d_in, const int* in_sizes, int n_in,
                              void* d_out, int out_size, void* d_ws, size_t ws_size,
                              hipStream_t stream) {
  const float* q   = (const float*)d_in[0];
  const float* k_  = (const float*)d_in[1];
  const float* v   = (const float*)d_in[2];
  const float* r_k = (const float*)d_in[3];
  const float* r_v = (const float*)d_in[4];
  const float* Wq  = (const float*)d_in[5];
  const float* bq  = (const float*)d_in[6];
  const float* Wk  = (const float*)d_in[7];
  const float* bk  = (const float*)d_in[8];
  const float* Wv  = (const float*)d_in[9];
  const float* bv  = (const float*)d_in[10];
  const float* Wrk = (const float*)d_in[11];
  // d_in[12] = brk: softmax-invariant, unused
  const float* Wrv = (const float*)d_in[13];
  const float* brv = (const float*)d_in[14];
  const float* Wo  = (const float*)d_in[15];
  const float* bo  = (const float*)d_in[16];
  (void)in_sizes; (void)n_in; (void)out_size;

  char* ws = (char*)d_ws;
  uint16_t* WqT  = (uint16_t*)(ws + (size_t)(0));
  uint16_t* WkT  = (uint16_t*)(ws + (size_t)(2u << 20));
  uint16_t* WvT  = (uint16_t*)(ws + (size_t)(4u << 20));
  uint16_t* WoT  = (uint16_t*)(ws + (size_t)(6u << 20));
  uint16_t* WrkB = (uint16_t*)(ws + (size_t)(8u << 20));
  uint16_t* WrvT = (uint16_t*)(ws + (size_t)(8u << 20) + (64u << 10));
  uint16_t* QH   = (uint16_t*)(ws + (size_t)(16u << 20));
  uint16_t* KH   = (uint16_t*)(ws + (size_t)(20u << 20));
  uint16_t* VHT  = (uint16_t*)(ws + (size_t)(24u << 20));
  uint16_t* QT   = (uint16_t*)(ws + (size_t)(28u << 20));
  uint16_t* VALB = (uint16_t*)(ws + (size_t)(36u << 20));
  uint16_t* V2   = (uint16_t*)(ws + (size_t)(16u << 20));  // QH slot, dead after score1
  uint16_t* SATT = (uint16_t*)(ws + (size_t)(40u << 20));  // 33.6 MB
  if (ws_size < (size_t)(74u << 20)) return;  // need 74 MB of scratch

  dim3 blk(256, 1, 1);
  k_prep<<<dim3(256, 5, 1), blk, 0, stream>>>(Wq, Wk, Wv, Wo, Wrk, Wrv,
                                              WqT, WkT, WvT, WoT, WrkB, WrvT);
  k_projqkv<<<dim3(16, 8, 3), blk, 0, stream>>>(q, k_, v, WqT, bq, bk, bv, QH);
  k_score1qt<<<dim3(16, 20, 4), blk, 0, stream>>>(QH, KH, WrkB, SATT, QT);
  k_s2v2<<<dim3(2048, 1, 1), blk, 0, stream>>>(QT, r_k, r_v, SATT, WrvT, brv, V2);
  k_val1<<<dim3(16, 16, 4), blk, 0, stream>>>(VHT, SATT, V2, VALB);
  k_out<<<dim3(16, 8, 1), blk, 0, stream>>>(VALB, WoT, bo, (float*)d_out);
}

// Round 9
// 341.359 us; speedup vs baseline: 1.1203x; 1.0104x over previous
//
#include <hip/hip_runtime.h>
#include <hip/hip_bf16.h>
#include <hip/hip_fp16.h>
#include <stdint.h>

// RelationMultiHeadAttention on MI355X.
// R9: k_score1qt S1 branch -> 256 blocks with nt-loop (qh staged once, kh
// double-buffered gll, single-barrier schedule); k_val1 dh merged (512 blocks,
// 4 d-frags). k_prep/k_projqkv/k_s2v2/k_out frozen from R8.
// Pipeline: k_prep -> k_projqkv -> k_score1qt -> k_s2v2 -> k_val1 -> k_out

typedef __attribute__((ext_vector_type(4))) float f32x4;
typedef __attribute__((ext_vector_type(8))) short s16x8;

#define MFMA16(A, B, C) __builtin_amdgcn_mfma_f32_16x16x32_bf16(A, B, C, 0, 0, 0)

__device__ __forceinline__ uint16_t f2bf(float x) {
  uint32_t u = __float_as_uint(x);
  u += 0x7fffu + ((u >> 16) & 1u);
  return (uint16_t)(u >> 16);
}
__device__ __forceinline__ float bf2f(uint16_t u) {
  return __uint_as_float((uint32_t)u << 16);
}
__device__ __forceinline__ uint16_t f2h(float x) {
  __half h = __float2half_rn(x);
  return *reinterpret_cast<uint16_t*>(&h);
}
__device__ __forceinline__ float h2f(uint16_t u) {
  __half h = *reinterpret_cast<__half*>(&u);
  return __half2float(h);
}

// v_cvt_pk_bf16_f32: two f32 -> packed 2x bf16 (RNE), 1 VALU op per pair.
__device__ __forceinline__ uint32_t cvtpk(float lo, float hi) {
  uint32_t r;
  asm("v_cvt_pk_bf16_f32 %0, %1, %2" : "=v"(r) : "v"(lo), "v"(hi));
  return r;
}

__device__ __forceinline__ s16x8 pack8(float4 a, float4 b) {
  union { uint32_t u[4]; s16x8 v; } r;
  r.u[0] = cvtpk(a.x, a.y);
  r.u[1] = cvtpk(a.z, a.w);
  r.u[2] = cvtpk(b.x, b.y);
  r.u[3] = cvtpk(b.z, b.w);
  return r.v;
}

__device__ __forceinline__ void gll16(const void* g, void* l) {
  __builtin_amdgcn_global_load_lds(
      (const __attribute__((address_space(1))) uint32_t*)(g),
      (__attribute__((address_space(3))) uint32_t*)(l), 16, 0, 0);
}

// ---------------------------------------------------------------------------
// K0: weight prep (unchanged).
// ---------------------------------------------------------------------------
__global__ __launch_bounds__(256) void k_prep(
    const float* __restrict__ Wq, const float* __restrict__ Wk,
    const float* __restrict__ Wv, const float* __restrict__ Wo,
    const float* __restrict__ Wrk, const float* __restrict__ Wrv,
    uint16_t* __restrict__ WqT, uint16_t* __restrict__ WkT,
    uint16_t* __restrict__ WvT, uint16_t* __restrict__ WoT,
    uint16_t* __restrict__ WrkB, uint16_t* __restrict__ WrvT) {
  int z = blockIdx.y;
  int t = threadIdx.x;
  if (z == 4) {
    if (blockIdx.x == 0) {
      for (int i = t; i < 128 * 64; i += 256) WrkB[i] = f2bf(Wrk[i]);
      for (int i = t; i < 64 * 128; i += 256) {
        int d = i >> 7, r = i & 127;
        WrvT[i] = f2bf(Wrv[r * 64 + d]);
      }
    }
    return;
  }
  const float* W = (z == 0) ? Wq : (z == 1) ? Wk : (z == 2) ? Wv : Wo;
  uint16_t* O = (z == 0) ? WqT : (z == 1) ? WkT : (z == 2) ? WvT : WoT;
  int tk = (blockIdx.x >> 4) * 64;
  int tn = (blockIdx.x & 15) * 64;
  __shared__ float tile[64][65];
  {
    int kk = t >> 2, c0 = (t & 3) * 16;
    const float* src = W + (size_t)(tk + kk) * 1024 + tn + c0;
#pragma unroll
    for (int i = 0; i < 16; i += 4) {
      float4 v = *(const float4*)(src + i);
      tile[kk][c0 + i + 0] = v.x; tile[kk][c0 + i + 1] = v.y;
      tile[kk][c0 + i + 2] = v.z; tile[kk][c0 + i + 3] = v.w;
    }
  }
  __syncthreads();
  {
    int n_loc = t >> 2;
    int n = tn + n_loc;
#pragma unroll
    for (int cc = 0; cc < 2; ++cc) {
      int c = (t & 3) * 2 + cc;
      int csrc = c ^ (n & 7);
      s16x8 pk;
#pragma unroll
      for (int j = 0; j < 8; ++j) pk[j] = (short)f2bf(tile[csrc * 8 + j][n_loc]);
      *reinterpret_cast<s16x8*>(O + (size_t)n * 1024 + tk + c * 8) = pk;
    }
  }
}

// ---------------------------------------------------------------------------
// K1: projections (unchanged from R8).
// ---------------------------------------------------------------------------
__global__ __launch_bounds__(256) void k_projqkv(
    const float* __restrict__ Xq, const float* __restrict__ Xk,
    const float* __restrict__ Xv, const uint16_t* __restrict__ WTbase,
    const float* __restrict__ bq, const float* __restrict__ bk,
    const float* __restrict__ bv, uint16_t* __restrict__ outbase) {
  int mode = blockIdx.z;
  const float* X = (mode == 0) ? Xq : (mode == 1) ? Xk : Xv;
  const float* bias = (mode == 0) ? bq : (mode == 1) ? bk : bv;
  const uint16_t* WT = WTbase + (size_t)mode * (1u << 20);
  uint16_t* out = outbase + (size_t)mode * (2u << 20);

  __shared__ alignas(16) float Xs[128 * 64];
  __shared__ alignas(16) uint16_t Bs[128 * 64];
  int t = threadIdx.x, lane = t & 63, w = t >> 6, lr = lane & 15, lg = lane >> 4;
  int m0 = blockIdx.x * 128, n0 = blockIdx.y * 128;
  int wm = (w >> 1) * 64, wn = (w & 1) * 64;
  f32x4 acc[4][4];
#pragma unroll
  for (int i = 0; i < 4; ++i)
#pragma unroll
    for (int j = 0; j < 4; ++j) acc[i][j] = (f32x4){0.f, 0.f, 0.f, 0.f};
  for (int ko = 0; ko < 16; ++ko) {
    __syncthreads();
    {
#pragma unroll
      for (int i = 0; i < 8; ++i) {
        int u = i * 256 + t;
        int row = u >> 4, c16 = u & 15;
        int cs = c16 ^ (row & 15);
        gll16(X + (size_t)(m0 + row) * 1024 + ko * 64 + cs * 4, (char*)Xs + u * 16);
      }
#pragma unroll
      for (int i = 0; i < 4; ++i) {
        int u = i * 256 + t;
        int row = u >> 3, c2 = u & 7;
        gll16(WT + (size_t)(n0 + row) * 1024 + ko * 64 + c2 * 8, (char*)Bs + u * 16);
      }
    }
    __syncthreads();
#pragma unroll
    for (int kk = 0; kk < 2; ++kk) {
      s16x8 af[4], bf[4];
#pragma unroll
      for (int mt = 0; mt < 4; ++mt) {
        int row = wm + mt * 16 + lr;
        int c0 = kk * 8 + lg * 2;
        float4 v0 = *(const float4*)((const char*)Xs + row * 256 +
                                     ((c0 ^ (row & 15)) * 16));
        float4 v1 = *(const float4*)((const char*)Xs + row * 256 +
                                     (((c0 + 1) ^ (row & 15)) * 16));
        af[mt] = pack8(v0, v1);
      }
#pragma unroll
      for (int nt = 0; nt < 4; ++nt) {
        int row = wn + nt * 16 + lr;
        bf[nt] = *(const s16x8*)((const char*)Bs + row * 128 +
                                 (((kk * 32 + lg * 8) * 2) ^ ((row & 7) << 4)));
      }
#pragma unroll
      for (int mt = 0; mt < 4; ++mt)
#pragma unroll
        for (int nt = 0; nt < 4; ++nt)
          acc[mt][nt] = MFMA16(af[mt], bf[nt], acc[mt][nt]);
    }
  }
  float sc = (mode == 1) ? 0.125f : 1.0f;
#pragma unroll
  for (int mt = 0; mt < 4; ++mt) {
#pragma unroll
    for (int nt = 0; nt < 4; ++nt) {
      int col = n0 + wn + nt * 16 + lr;
      float bcol = bias[col];
      if (mode != 2) {
#pragma unroll
        for (int r = 0; r < 4; ++r) {
          int row = m0 + wm + mt * 16 + lg * 4 + r;
          out[(size_t)row * 1024 + col] = f2bf((acc[mt][nt][r] + bcol) * sc);
        }
      } else {
        int row0 = m0 + wm + mt * 16 + lg * 4;
        int b = row0 >> 9, n = row0 & 511;
        int h = col >> 6, d = col & 63;
        ushort4 pk;
        pk.x = f2bf(acc[mt][nt][0] + bcol);
        pk.y = f2bf(acc[mt][nt][1] + bcol);
        pk.z = f2bf(acc[mt][nt][2] + bcol);
        pk.w = f2bf(acc[mt][nt][3] + bcol);
        *reinterpret_cast<ushort4*>(out + ((size_t)(b * 16 + h) * 64 + d) * 512 + n) = pk;
      }
    }
  }
}

// ---------------------------------------------------------------------------
// K2: fused S1 GEMM + qt GEMM.
// x<4: S1 (mt=x, h=y, b=z): qh tile staged once; nt-loop over 4 kh tiles,
//      double-buffered gll, schedule {vmcnt(0); barrier; stage nt+1; consume nt}.
// x in {4,5}: qt slot = (x-4)*64 + y*4 + z, 256 rows each.
// ---------------------------------------------------------------------------
__global__ __launch_bounds__(256) void k_score1qt(
    const uint16_t* __restrict__ qh, const uint16_t* __restrict__ kh,
    const uint16_t* __restrict__ WrkB, uint16_t* __restrict__ S1,
    uint16_t* __restrict__ qt) {
  __shared__ alignas(16) uint16_t Qs[128 * 64];      // 16KB
  __shared__ alignas(16) uint16_t Ks[2][128 * 64];   // 32KB double buffer
  int t = threadIdx.x, lane = t & 63, w = t >> 6, lr = lane & 15, lg = lane >> 4;
  int b = blockIdx.z;
  if (blockIdx.x >= 4) {
    // ---- qt branch: 128 slots x 256 rows
    int slot = (blockIdx.x - 4) * 64 + blockIdx.y * 4 + b;
#pragma unroll
    for (int it = 0; it < 4; ++it) {
      int row0 = slot * 256 + it * 64 + w * 16;
      f32x4 acc[8];
#pragma unroll
      for (int i = 0; i < 8; ++i) acc[i] = (f32x4){0.f, 0.f, 0.f, 0.f};
      s16x8 af[2];
#pragma unroll
      for (int kk = 0; kk < 2; ++kk)
        af[kk] = *(const s16x8*)(qh + (size_t)(row0 + lr) * 64 + kk * 32 + lg * 8);
#pragma unroll
      for (int rt = 0; rt < 8; ++rt) {
#pragma unroll
        for (int kk = 0; kk < 2; ++kk) {
          s16x8 bf = *(const s16x8*)(WrkB + (size_t)(rt * 16 + lr) * 64 + kk * 32 + lg * 8);
          acc[rt] = MFMA16(af[kk], bf, acc[rt]);
        }
      }
#pragma unroll
      for (int rt = 0; rt < 8; ++rt)
#pragma unroll
        for (int r = 0; r < 4; ++r)
          qt[(size_t)(row0 + lg * 4 + r) * 128 + rt * 16 + lr] = f2bf(acc[rt][r]);
    }
    return;
  }
  // ---- S1 branch
  int mt = blockIdx.x, h = blockIdx.y;
  int m0 = mt * 128;
  const char* qg = (const char*)(qh + (size_t)(b * 512 + m0) * 1024 + h * 64);
  const char* kg = (const char*)(kh + (size_t)b * 512 * 1024 + h * 64);
  // stage qh once + kh tile 0
#pragma unroll
  for (int i = 0; i < 4; ++i) {
    int u = i * 256 + t;
    int row = u >> 3;
    int cs = (u & 7) ^ (row & 7);
    gll16(qg + (size_t)row * 2048 + cs * 16, (char*)Qs + u * 16);
    gll16(kg + (size_t)row * 2048 + cs * 16, (char*)Ks[0] + u * 16);
  }
  int wm = (w >> 1) * 64, wn = (w & 1) * 64;
  int hsw = (h & 7) << 3;
#pragma unroll
  for (int nt = 0; nt < 4; ++nt) {
    asm volatile("s_waitcnt vmcnt(0)" ::: "memory");
    __builtin_amdgcn_s_barrier();
    asm volatile("" ::: "memory");
    if (nt < 3) {  // stage kh(nt+1); Ks[(nt+1)&1] fully consumed (barrier above)
      const char* kgn = kg + (size_t)(nt + 1) * 128 * 2048;
#pragma unroll
      for (int i = 0; i < 4; ++i) {
        int u = i * 256 + t;
        int row = u >> 3;
        int cs = (u & 7) ^ (row & 7);
        gll16(kgn + (size_t)row * 2048 + cs * 16, (char*)Ks[(nt + 1) & 1] + u * 16);
      }
    }
    f32x4 acc[4][4];
#pragma unroll
    for (int i = 0; i < 4; ++i)
#pragma unroll
      for (int j = 0; j < 4; ++j) acc[i][j] = (f32x4){0.f, 0.f, 0.f, 0.f};
#pragma unroll
    for (int kk = 0; kk < 2; ++kk) {
      s16x8 af[4], bf[4];
#pragma unroll
      for (int mtt = 0; mtt < 4; ++mtt) {
        int row = wm + mtt * 16 + lr;
        af[mtt] = *(const s16x8*)((const char*)Qs + row * 128 +
                                  (((kk * 4 + lg) ^ (row & 7)) * 16));
      }
#pragma unroll
      for (int ntt = 0; ntt < 4; ++ntt) {
        int row = wn + ntt * 16 + lr;
        bf[ntt] = *(const s16x8*)((const char*)Ks[nt & 1] + row * 128 +
                                  (((kk * 4 + lg) ^ (row & 7)) * 16));
      }
      // MFMA16(B,A): D row-dim <-> kh rows (n), col <-> qh rows (m)
#pragma unroll
      for (int mtt = 0; mtt < 4; ++mtt)
#pragma unroll
        for (int ntt = 0; ntt < 4; ++ntt)
          acc[mtt][ntt] = MFMA16(bf[ntt], af[mtt], acc[mtt][ntt]);
    }
#pragma unroll
    for (int mtt = 0; mtt < 4; ++mtt) {
#pragma unroll
      for (int ntt = 0; ntt < 4; ++ntt) {
        int m = b * 512 + m0 + wm + mtt * 16 + lr;
        int nsw = (nt * 128 + wn + ntt * 16 + lg * 4) ^ hsw;
        ushort4 u4;
        u4.x = f2h(acc[mtt][ntt][0]); u4.y = f2h(acc[mtt][ntt][1]);
        u4.z = f2h(acc[mtt][ntt][2]); u4.w = f2h(acc[mtt][ntt][3]);
        *(ushort4*)(S1 + (size_t)m * 8192 + h * 512 + nsw) = u4;
      }
    }
  }
}

// ---------------------------------------------------------------------------
// K3: per-(b,m) relation streams (unchanged from R8).
// ---------------------------------------------------------------------------
#define RKSTEP(s)                                                              \
  {                                                                            \
    asm volatile("s_waitcnt vmcnt(%0)" ::                                      \
                 "i"(((s) < 2) ? 6 : (((s) < 31) ? 2 : 0)) : "memory");        \
    const char* bp_ = wpriv + ((s) & 1) * 2048 + lr * 128;                     \
    float4 v0_ = *(const float4*)(bp_ + (((lg * 2 + 0) ^ (lr & 7)) * 16));     \
    float4 v1_ = *(const float4*)(bp_ + (((lg * 2 + 1) ^ (lr & 7)) * 16));     \
    acc[(s) >> 2] = MFMA16(aqt[(s) & 3], pack8(v0_, v1_), acc[(s) >> 2]);      \
    if ((s) + 2 < 32) {                                                        \
      const int s2_ = (s) + 2;                                                 \
      const char* src_ = rkb + (size_t)((s2_ >> 2) * 64 + w * 16 + r_lo) * 512 \
                         + (s2_ & 3) * 128 + c16s * 16;                        \
      char* dst_ = wpriv + (s2_ & 1) * 2048 + lane * 16;                       \
      gll16(src_, dst_);                                                       \
      gll16(src_ + 8 * 512, dst_ + 1024);                                      \
    }                                                                          \
  }

#define RVI(c)                                                                 \
  { _Pragma("unroll")                                                          \
    for (int i_ = 0; i_ < 2; ++i_) {                                           \
      int u_ = i_ * 64 + lane;                                                 \
      gll16(rvb + (size_t)(((c) >> 1) * 32 + (u_ >> 2)) * 512 + w * 128 +      \
                ((c) & 1) * 64 + (u_ & 3) * 16,                                \
            wpriv + ((c) & 1) * 2048 + u_ * 16);                               \
    } }

#define RVC(c, accv)                                                           \
  {                                                                            \
    s16x8 a_ = *(const s16x8*)((const char*)att_lds + lr * 1024 +              \
        (((uint32_t)(((c) >> 1) * 64 + lg * 16)) ^ ((uint32_t)(lr & 7) << 4)));\
    const float* vb_ = (const float*)(wpriv + ((c) & 1) * 2048);               \
    union { uint32_t u[4]; s16x8 v; } bb_;                                     \
    _Pragma("unroll")                                                          \
    for (int i = 0; i < 4; ++i)                                                \
      bb_.u[i] = cvtpk(vb_[(lg * 8 + 2 * i) * 16 + lr],                        \
                       vb_[(lg * 8 + 2 * i + 1) * 16 + lr]);                   \
    accv = MFMA16(a_, bb_.v, accv);                                            \
  }

__global__ __launch_bounds__(256, 4) void k_s2v2(
    const uint16_t* __restrict__ qt, const float* __restrict__ rk,
    const float* __restrict__ rv, uint16_t* SATT,
    const uint16_t* __restrict__ WrvT, const float* __restrict__ brv,
    uint16_t* __restrict__ V2) {
  int bm = blockIdx.x;
  int t = threadIdx.x, lane = t & 63, w = t >> 6, lr = lane & 15, lg = lane >> 4;
  __shared__ alignas(16) char stream_lds[16384];
  __shared__ alignas(16) uint16_t att_lds[16 * 512];
  __shared__ alignas(16) uint16_t arv_lds[16 * 128];
  __shared__ float red[2][16][4];
  char* wpriv = stream_lds + w * 4096;
  const int r_lo = lane >> 3;
  const int c16s = (lane & 7) ^ r_lo;

  s16x8 aqt[4];
#pragma unroll
  for (int kk = 0; kk < 4; ++kk)
    aqt[kk] = *(const s16x8*)(qt + ((size_t)bm * 16 + lr) * 128 + kk * 32 + lg * 8);

  const char* rkb = (const char*)(rk + (size_t)bm * 65536);
#pragma unroll
  for (int s2 = 0; s2 < 2; ++s2) {
    const char* src_ = rkb + (size_t)(w * 16 + r_lo) * 512 + s2 * 128 + c16s * 16;
    char* dst_ = wpriv + s2 * 2048 + lane * 16;
    gll16(src_, dst_);
    gll16(src_ + 8 * 512, dst_ + 1024);
  }
  const char* s1g = (const char*)(SATT + (size_t)bm * 8192);
#pragma unroll
  for (int i = 0; i < 4; ++i)
    gll16(s1g + i * 4096 + t * 16, (char*)att_lds + i * 4096 + t * 16);

  f32x4 acc[8];
#pragma unroll
  for (int j = 0; j < 8; ++j) acc[j] = (f32x4){0.f, 0.f, 0.f, 0.f};

  RKSTEP(0)  RKSTEP(1)  RKSTEP(2)  RKSTEP(3)  RKSTEP(4)  RKSTEP(5)  RKSTEP(6)  RKSTEP(7)
  RKSTEP(8)  RKSTEP(9)  RKSTEP(10) RKSTEP(11) RKSTEP(12) RKSTEP(13) RKSTEP(14) RKSTEP(15)
  RKSTEP(16) RKSTEP(17) RKSTEP(18) RKSTEP(19) RKSTEP(20) RKSTEP(21) RKSTEP(22) RKSTEP(23)
  RKSTEP(24) RKSTEP(25) RKSTEP(26) RKSTEP(27) RKSTEP(28) RKSTEP(29) RKSTEP(30) RKSTEP(31)

  __syncthreads();

  const char* rvb = (const char*)(rv + (size_t)bm * 65536);
  RVI(0) RVI(1)

#pragma unroll
  for (int idx = 0; idx < 8; ++idx) {
#pragma unroll
    for (int r = 0; r < 4; ++r) {
      int h = lg * 4 + r;
      int n = idx * 64 + w * 16 + lr;
      uint16_t s1v = *(const uint16_t*)((const char*)att_lds + h * 1024 +
                     (((uint32_t)n * 2) ^ ((uint32_t)(h & 7) << 4)));
      acc[idx][r] += h2f(s1v);
    }
  }

  float mrow[4], inv[4];
#pragma unroll
  for (int r = 0; r < 4; ++r) {
    float mx = acc[0][r];
#pragma unroll
    for (int j = 1; j < 8; ++j) mx = fmaxf(mx, acc[j][r]);
#pragma unroll
    for (int off = 1; off < 16; off <<= 1) mx = fmaxf(mx, __shfl_xor(mx, off, 64));
    mrow[r] = mx;
  }
  if (lr == 0) {
#pragma unroll
    for (int r = 0; r < 4; ++r) red[0][lg * 4 + r][w] = mrow[r];
  }
  __syncthreads();
#pragma unroll
  for (int r = 0; r < 4; ++r) {
    const float* p = red[0][lg * 4 + r];
    mrow[r] = fmaxf(fmaxf(p[0], p[1]), fmaxf(p[2], p[3]));
  }
#pragma unroll
  for (int r = 0; r < 4; ++r) {
    float s = 0.f;
#pragma unroll
    for (int j = 0; j < 8; ++j) {
      float pj = __expf(acc[j][r] - mrow[r]);
      acc[j][r] = pj;
      s += pj;
    }
#pragma unroll
    for (int off = 1; off < 16; off <<= 1) s += __shfl_xor(s, off, 64);
    inv[r] = s;
  }
  if (lr == 0) {
#pragma unroll
    for (int r = 0; r < 4; ++r) red[1][lg * 4 + r][w] = inv[r];
  }
  __syncthreads();
#pragma unroll
  for (int r = 0; r < 4; ++r) {
    const float* p = red[1][lg * 4 + r];
    inv[r] = 1.f / (p[0] + p[1] + p[2] + p[3]);
  }
#pragma unroll
  for (int r = 0; r < 4; ++r) {
    int h = lg * 4 + r;
#pragma unroll
    for (int idx = 0; idx < 8; ++idx) {
      int n = idx * 64 + w * 16 + lr;
      uint32_t off = (uint32_t)h * 1024 + (((uint32_t)n * 2) ^ ((uint32_t)(h & 7) << 4));
      *(uint16_t*)((char*)att_lds + off) = f2bf(acc[idx][r] * inv[r]);
    }
  }
  __syncthreads();

  f32x4 arv0 = (f32x4){0.f, 0.f, 0.f, 0.f}, arv1 = arv0;
#pragma unroll 1
  for (int cp = 0; cp < 14; ++cp) {
    asm volatile("s_waitcnt vmcnt(2)" ::: "memory");
    RVC(2 * cp, arv0)
    RVI(2 * cp + 2)
    asm volatile("s_waitcnt vmcnt(2)" ::: "memory");
    RVC(2 * cp + 1, arv1)
    RVI(2 * cp + 3)
  }
  asm volatile("s_waitcnt vmcnt(2)" ::: "memory");
  RVC(28, arv0)
  RVI(30)
  asm volatile("s_waitcnt vmcnt(2)" ::: "memory");
  RVC(29, arv1)
  RVI(31)
  asm volatile("s_waitcnt vmcnt(2)" ::: "memory");
  RVC(30, arv0)
  asm volatile("s_waitcnt vmcnt(0)" ::: "memory");
  RVC(31, arv1)

#pragma unroll
  for (int r = 0; r < 4; ++r) {
    int h = lg * 4 + r;
    uint32_t rc0 = (uint32_t)(w * 32 + lr) * 2;
    uint32_t rc1 = (uint32_t)(w * 32 + 16 + lr) * 2;
    *(uint16_t*)((char*)arv_lds + h * 256 + (rc0 ^ ((uint32_t)(h & 7) << 4))) = f2bf(arv0[r]);
    *(uint16_t*)((char*)arv_lds + h * 256 + (rc1 ^ ((uint32_t)(h & 7) << 4))) = f2bf(arv1[r]);
  }
  __syncthreads();
  f32x4 vacc = (f32x4){0.f, 0.f, 0.f, 0.f};
#pragma unroll
  for (int kk = 0; kk < 4; ++kk) {
    uint32_t rb = (uint32_t)(kk * 32 + lg * 8) * 2;
    s16x8 a = *(const s16x8*)((const char*)arv_lds + lr * 256 +
                              (rb ^ ((uint32_t)(lr & 7) << 4)));
    s16x8 bfw = *(const s16x8*)(WrvT + (size_t)(w * 16 + lr) * 128 + kk * 32 + lg * 8);
    vacc = MFMA16(a, bfw, vacc);
  }
  float bias = brv[w * 16 + lr];
#pragma unroll
  for (int r = 0; r < 4; ++r)
    V2[(size_t)bm * 1024 + (lg * 4 + r) * 64 + w * 16 + lr] = f2bf(vacc[r] + bias);

#pragma unroll
  for (int i = 0; i < 4; ++i) {
    s16x8 vv = *(const s16x8*)((const char*)att_lds + i * 4096 + t * 16);
    *(s16x8*)((char*)SATT + (size_t)bm * 16384 + i * 4096 + t * 16) = vv;
  }
}

// ---------------------------------------------------------------------------
// K4: val = att @ vh + V2 -> VALB. Grid (8,16,4); 4 d-frags per wave.
// ---------------------------------------------------------------------------
__global__ __launch_bounds__(256, 4) void k_val1(
    const uint16_t* __restrict__ vhT, const uint16_t* __restrict__ ATT,
    const uint16_t* __restrict__ V2, uint16_t* __restrict__ VALB) {
  int t = threadIdx.x, lane = t & 63, w = t >> 6, lr = lane & 15, lg = lane >> 4;
  int mt = blockIdx.x, h = blockIdx.y, b = blockIdx.z;
  int mb = mt * 64 + w * 16;
  const uint16_t* vrow = vhT + ((size_t)((b * 16 + h) * 64) + lr) * 512 + lg * 8;
  const uint16_t* arow = ATT + (size_t)(b * 512 + mb + lr) * 8192 + h * 512;
  f32x4 acc[4];
#pragma unroll
  for (int j = 0; j < 4; ++j) acc[j] = (f32x4){0.f, 0.f, 0.f, 0.f};
#pragma unroll 4
  for (int kk = 0; kk < 16; ++kk) {
    int nsw = (kk * 32 + lg * 8) ^ ((h & 7) << 3);
    s16x8 a0 = *(const s16x8*)(arow + nsw);
#pragma unroll
    for (int dt = 0; dt < 4; ++dt) {
      s16x8 vf = *(const s16x8*)(vrow + (size_t)dt * 16 * 512 + kk * 32);
      acc[dt] = MFMA16(vf, a0, acc[dt]);
    }
  }
#pragma unroll
  for (int dt = 0; dt < 4; ++dt) {
    size_t adr = (size_t)(b * 512 + mb + lr) * 1024 + h * 64 + dt * 16 + lg * 4;
    ushort4 v2v = *(const ushort4*)(V2 + adr);
    ushort4 o;
    o.x = f2bf(acc[dt][0] + bf2f(v2v.x));
    o.y = f2bf(acc[dt][1] + bf2f(v2v.y));
    o.z = f2bf(acc[dt][2] + bf2f(v2v.z));
    o.w = f2bf(acc[dt][3] + bf2f(v2v.w));
    *(ushort4*)(VALB + adr) = o;
  }
}

// ---------------------------------------------------------------------------
// K5: out = VAL @ Wo + bo (unchanged from R8).
// ---------------------------------------------------------------------------
__global__ __launch_bounds__(256) void k_out(
    const uint16_t* __restrict__ A, const uint16_t* __restrict__ WT,
    const float* __restrict__ bias, float* __restrict__ out) {
  __shared__ alignas(16) uint16_t As[128 * 64];
  __shared__ alignas(16) uint16_t Bs[128 * 64];
  int t = threadIdx.x, lane = t & 63, w = t >> 6, lr = lane & 15, lg = lane >> 4;
  int m0 = blockIdx.x * 128, n0 = blockIdx.y * 128;
  int wm = (w >> 1) * 64, wn = (w & 1) * 64;
  f32x4 acc[4][4];
#pragma unroll
  for (int i = 0; i < 4; ++i)
#pragma unroll
    for (int j = 0; j < 4; ++j) acc[i][j] = (f32x4){0.f, 0.f, 0.f, 0.f};
  for (int ko = 0; ko < 16; ++ko) {
    __syncthreads();
    {
#pragma unroll
      for (int i = 0; i < 4; ++i) {
        int u = i * 256 + t;
        int row = u >> 3, c2 = u & 7;
        int cs = c2 ^ (row & 7);
        gll16(A + (size_t)(m0 + row) * 1024 + ko * 64 + cs * 8, (char*)As + u * 16);
        gll16(WT + (size_t)(n0 + row) * 1024 + ko * 64 + c2 * 8, (char*)Bs + u * 16);
      }
    }
    __syncthreads();
#pragma unroll
    for (int kk = 0; kk < 2; ++kk) {
      s16x8 af[4], bf[4];
#pragma unroll
      for (int mt = 0; mt < 4; ++mt) {
        int row = wm + mt * 16 + lr;
        af[mt] = *(const s16x8*)((const char*)As + row * 128 +
                                 (((kk * 32 + lg * 8) * 2) ^ ((row & 7) << 4)));
      }
#pragma unroll
      for (int nt = 0; nt < 4; ++nt) {
        int row = wn + nt * 16 + lr;
        bf[nt] = *(const s16x8*)((const char*)Bs + row * 128 +
                                 (((kk * 32 + lg * 8) * 2) ^ ((row & 7) << 4)));
      }
#pragma unroll
      for (int mt = 0; mt < 4; ++mt)
#pragma unroll
        for (int nt = 0; nt < 4; ++nt)
          acc[mt][nt] = MFMA16(af[mt], bf[nt], acc[mt][nt]);
    }
  }
#pragma unroll
  for (int mt = 0; mt < 4; ++mt) {
#pragma unroll
    for (int nt = 0; nt < 4; ++nt) {
      int col = n0 + wn + nt * 16 + lr;
      float bcol = bias[col];
#pragma unroll
      for (int r = 0; r < 4; ++r) {
        int row = m0 + wm + mt * 16 + lg * 4 + r;
        out[(size_t)row * 1024 + col] = acc[mt][nt][r] + bcol;
      }
    }
  }
}

// ---------------------------------------------------------------------------
extern "C" void kernel_launch(void* const* d_in, const int* in_sizes, int n_in,
                              void* d_out, int out_size, void* d_ws, size_t ws_size,
                              hipStream_t stream) {
  const float* q   = (const float*)d_in[0];
  const float* k_  = (const float*)d_in[1];
  const float* v   = (const float*)d_in[2];
  const float* r_k = (const float*)d_in[3];
  const float* r_v = (const float*)d_in[4];
  const float* Wq  = (const float*)d_in[5];
  const float* bq  = (const float*)d_in[6];
  const float* Wk  = (const float*)d_in[7];
  const float* bk  = (const float*)d_in[8];
  const float* Wv  = (const float*)d_in[9];
  const float* bv  = (const float*)d_in[10];
  const float* Wrk = (const float*)d_in[11];
  // d_in[12] = brk: softmax-invariant, unused
  const float* Wrv = (const float*)d_in[13];
  const float* brv = (const float*)d_in[14];
  const float* Wo  = (const float*)d_in[15];
  const float* bo  = (const float*)d_in[16];
  (void)in_sizes; (void)n_in; (void)out_size;

  char* ws = (char*)d_ws;
  uint16_t* WqT  = (uint16_t*)(ws + (size_t)(0));
  uint16_t* WkT  = (uint16_t*)(ws + (size_t)(2u << 20));
  uint16_t* WvT  = (uint16_t*)(ws + (size_t)(4u << 20));
  uint16_t* WoT  = (uint16_t*)(ws + (size_t)(6u << 20));
  uint16_t* WrkB = (uint16_t*)(ws + (size_t)(8u << 20));
  uint16_t* WrvT = (uint16_t*)(ws + (size_t)(8u << 20) + (64u << 10));
  uint16_t* QH   = (uint16_t*)(ws + (size_t)(16u << 20));
  uint16_t* KH   = (uint16_t*)(ws + (size_t)(20u << 20));
  uint16_t* VHT  = (uint16_t*)(ws + (size_t)(24u << 20));
  uint16_t* QT   = (uint16_t*)(ws + (size_t)(28u << 20));
  uint16_t* VALB = (uint16_t*)(ws + (size_t)(36u << 20));
  uint16_t* V2   = (uint16_t*)(ws + (size_t)(16u << 20));  // QH slot, dead after score1
  uint16_t* SATT = (uint16_t*)(ws + (size_t)(40u << 20));  // 33.6 MB
  if (ws_size < (size_t)(74u << 20)) return;  // need 74 MB of scratch

  dim3 blk(256, 1, 1);
  k_prep<<<dim3(256, 5, 1), blk, 0, stream>>>(Wq, Wk, Wv, Wo, Wrk, Wrv,
                                              WqT, WkT, WvT, WoT, WrkB, WrvT);
  k_projqkv<<<dim3(16, 8, 3), blk, 0, stream>>>(q, k_, v, WqT, bq, bk, bv, QH);
  k_score1qt<<<dim3(6, 16, 4), blk, 0, stream>>>(QH, KH, WrkB, SATT, QT);
  k_s2v2<<<dim3(2048, 1, 1), blk, 0, stream>>>(QT, r_k, r_v, SATT, WrvT, brv, V2);
  k_val1<<<dim3(8, 16, 4), blk, 0, stream>>>(VHT, SATT, V2, VALB);
  k_out<<<dim3(16, 8, 1), blk, 0, stream>>>(VALB, WoT, bo, (float*)d_out);
}